// Round 1
// baseline (1494.178 us; speedup 1.0000x reference)
//
#include <hip/hip_runtime.h>
#include <math.h>

// Problem constants
constexpr int Bc = 8;
constexpr int Tt = 1025;
constexpr int Cc = 512;
constexpr int Hn = 8;
constexpr int CA = 256;
constexpr int Ll = 256;

enum { EP_NONE = 0, EP_SIGMOID = 1, EP_GELU = 2 };

// ---------------------------------------------------------------------------
// Generic fp32 tiled GEMM: Cout[M,N] = A[M,K](lda) @ W[K,N] + bias, epilogue.
// 64x64 tile, BK=16, 256 threads, 4x4 micro-tile per thread.
// ---------------------------------------------------------------------------
__global__ __launch_bounds__(256) void gemm_bias(
    const float* __restrict__ A, int lda,
    const float* __restrict__ W, const float* __restrict__ bias,
    float* __restrict__ Cout, int M, int N, int K, int ep)
{
  __shared__ float As[16][68];  // transposed A tile; stride 68 keeps float4 align
  __shared__ float Bs[16][64];

  const int m0 = blockIdx.y * 64;
  const int n0 = blockIdx.x * 64;
  const int tid = threadIdx.x;
  const int tx = tid & 15;
  const int ty = tid >> 4;
  const int a_row = tid >> 2;        // 0..63
  const int a_col = (tid & 3) << 2;  // 0,4,8,12
  const int b_row = tid >> 4;        // 0..15
  const int b_col = (tid & 15) << 2; // 0..60

  float acc[4][4];
  #pragma unroll
  for (int i = 0; i < 4; i++)
    #pragma unroll
    for (int j = 0; j < 4; j++) acc[i][j] = 0.f;

  for (int k0 = 0; k0 < K; k0 += 16) {
    const int gm = m0 + a_row;
    float4 av;
    if (gm < M) av = *(const float4*)(A + (size_t)gm * lda + (k0 + a_col));
    else        av = make_float4(0.f, 0.f, 0.f, 0.f);
    As[a_col + 0][a_row] = av.x;
    As[a_col + 1][a_row] = av.y;
    As[a_col + 2][a_row] = av.z;
    As[a_col + 3][a_row] = av.w;

    const float4 bv = *(const float4*)(W + (size_t)(k0 + b_row) * N + (n0 + b_col));
    Bs[b_row][b_col + 0] = bv.x;
    Bs[b_row][b_col + 1] = bv.y;
    Bs[b_row][b_col + 2] = bv.z;
    Bs[b_row][b_col + 3] = bv.w;
    __syncthreads();

    #pragma unroll
    for (int kk = 0; kk < 16; kk++) {
      const float4 a4 = *(const float4*)&As[kk][ty << 2];
      const float4 b4 = *(const float4*)&Bs[kk][tx << 2];
      const float ar[4] = {a4.x, a4.y, a4.z, a4.w};
      const float br[4] = {b4.x, b4.y, b4.z, b4.w};
      #pragma unroll
      for (int i = 0; i < 4; i++)
        #pragma unroll
        for (int j = 0; j < 4; j++) acc[i][j] += ar[i] * br[j];
    }
    __syncthreads();
  }

  #pragma unroll
  for (int i = 0; i < 4; i++) {
    const int gm = m0 + (ty << 2) + i;
    if (gm >= M) break;
    float o[4];
    #pragma unroll
    for (int j = 0; j < 4; j++) {
      float v = acc[i][j] + bias[n0 + (tx << 2) + j];
      if (ep == EP_SIGMOID)    v = 1.f / (1.f + __expf(-v));
      else if (ep == EP_GELU)  v = 0.5f * v * (1.f + erff(v * 0.70710678118654752f));
      o[j] = v;
    }
    *(float4*)(Cout + (size_t)gm * N + n0 + (tx << 2)) = make_float4(o[0], o[1], o[2], o[3]);
  }
}

// ---------------------------------------------------------------------------
// Flash attention: one block per (q-tile of 32, b*h). Online softmax.
// Q:(B,Tq,H*DH) K,V:(B,Tk,H*DH) O:(B,Tq,H*DH); row stride = H*DH.
// ---------------------------------------------------------------------------
template <int DH>
__global__ __launch_bounds__(256) void attn_flash(
    const float* __restrict__ Q, const float* __restrict__ K,
    const float* __restrict__ V, float* __restrict__ O,
    int Tq, int Tk, float scale, int qbs, int kbs)
{
  constexpr int QT = 32, KT = 32;
  constexpr int NG = 256 / DH;   // lane groups
  constexpr int RPG = QT / NG;   // q-rows per group

  const int b = blockIdx.y / Hn;
  const int h = blockIdx.y % Hn;
  const int q0 = blockIdx.x * QT;
  const int qs = Hn * DH;  // row stride (same for q/k/v/o here)

  const float* Qb = Q + (size_t)b * qbs + h * DH;
  const float* Kb = K + (size_t)b * kbs + h * DH;
  const float* Vb = V + (size_t)b * kbs + h * DH;
  float*       Ob = O + (size_t)b * qbs + h * DH;

  __shared__ float Qs[QT][DH + 4];
  __shared__ float Ks[KT][DH + 4];
  __shared__ float Vs[KT][DH + 4];
  __shared__ float S[QT][36];
  __shared__ float mrow[QT], lrow[QT], crow[QT];

  const int tid = threadIdx.x;
  const int d = tid % DH;
  const int g = tid / DH;

  #pragma unroll
  for (int r = g; r < QT; r += NG) {
    const int gq = q0 + r;
    Qs[r][d] = (gq < Tq) ? Qb[(size_t)gq * qs + d] : 0.f;
  }
  if (tid < QT) { mrow[tid] = -1e30f; lrow[tid] = 0.f; }

  float acc[RPG];
  #pragma unroll
  for (int r = 0; r < RPG; r++) acc[r] = 0.f;

  const int sqr = tid & 31;         // score row
  const int skc = (tid >> 5) << 2;  // score col base (4 cols per thread)
  const int srow = tid >> 3;        // softmax row
  const int ssub = tid & 7;         // softmax sub-lane (8 per row)

  for (int k0 = 0; k0 < Tk; k0 += KT) {
    __syncthreads();  // previous PV done before overwriting Ks/Vs/S
    for (int r = g; r < KT; r += NG) {
      const int gk = k0 + r;
      if (gk < Tk) {
        Ks[r][d] = Kb[(size_t)gk * qs + d];
        Vs[r][d] = Vb[(size_t)gk * qs + d];
      } else {
        Ks[r][d] = 0.f;
        Vs[r][d] = 0.f;
      }
    }
    __syncthreads();

    // ---- scores: S[sqr][skc..skc+3] = scale * q.k ----
    float s0 = 0.f, s1 = 0.f, s2 = 0.f, s3 = 0.f;
    #pragma unroll
    for (int dd = 0; dd < DH; dd += 4) {
      const float4 qv  = *(const float4*)&Qs[sqr][dd];
      const float4 k0v = *(const float4*)&Ks[skc + 0][dd];
      const float4 k1v = *(const float4*)&Ks[skc + 1][dd];
      const float4 k2v = *(const float4*)&Ks[skc + 2][dd];
      const float4 k3v = *(const float4*)&Ks[skc + 3][dd];
      s0 += qv.x * k0v.x + qv.y * k0v.y + qv.z * k0v.z + qv.w * k0v.w;
      s1 += qv.x * k1v.x + qv.y * k1v.y + qv.z * k1v.z + qv.w * k1v.w;
      s2 += qv.x * k2v.x + qv.y * k2v.y + qv.z * k2v.z + qv.w * k2v.w;
      s3 += qv.x * k3v.x + qv.y * k3v.y + qv.z * k3v.z + qv.w * k3v.w;
    }
    {
      const int base = k0 + skc;
      S[sqr][skc + 0] = (base + 0 < Tk) ? s0 * scale : -1e30f;
      S[sqr][skc + 1] = (base + 1 < Tk) ? s1 * scale : -1e30f;
      S[sqr][skc + 2] = (base + 2 < Tk) ? s2 * scale : -1e30f;
      S[sqr][skc + 3] = (base + 3 < Tk) ? s3 * scale : -1e30f;
    }
    __syncthreads();

    // ---- online softmax (8 lanes per row) ----
    {
      float sv[4];
      float mx = -1e30f;
      #pragma unroll
      for (int jj = 0; jj < 4; jj++) {
        sv[jj] = S[srow][ssub * 4 + jj];
        mx = fmaxf(mx, sv[jj]);
      }
      mx = fmaxf(mx, __shfl_xor(mx, 1));
      mx = fmaxf(mx, __shfl_xor(mx, 2));
      mx = fmaxf(mx, __shfl_xor(mx, 4));
      const float mold = mrow[srow];
      const float mnew = fmaxf(mold, mx);
      float lsum = 0.f;
      #pragma unroll
      for (int jj = 0; jj < 4; jj++) {
        const float p = __expf(sv[jj] - mnew);
        S[srow][ssub * 4 + jj] = p;
        lsum += p;
      }
      lsum += __shfl_xor(lsum, 1);
      lsum += __shfl_xor(lsum, 2);
      lsum += __shfl_xor(lsum, 4);
      if (ssub == 0) {
        const float corr = __expf(mold - mnew);
        crow[srow] = corr;
        lrow[srow] = lrow[srow] * corr + lsum;
        mrow[srow] = mnew;
      }
    }
    __syncthreads();

    // ---- rescale + PV accumulate ----
    #pragma unroll
    for (int r = 0; r < RPG; r++) acc[r] *= crow[g * RPG + r];
    #pragma unroll
    for (int j0 = 0; j0 < KT; j0 += 4) {
      const float v0 = Vs[j0 + 0][d];
      const float v1 = Vs[j0 + 1][d];
      const float v2 = Vs[j0 + 2][d];
      const float v3 = Vs[j0 + 3][d];
      #pragma unroll
      for (int r = 0; r < RPG; r++) {
        const float4 p = *(const float4*)&S[g * RPG + r][j0];
        acc[r] += p.x * v0 + p.y * v1 + p.z * v2 + p.w * v3;
      }
    }
  }
  __syncthreads();

  #pragma unroll
  for (int r = 0; r < RPG; r++) {
    const int qr = g * RPG + r;
    const int gq = q0 + qr;
    if (gq < Tq) Ob[(size_t)gq * qs + d] = acc[r] / lrow[qr];
  }
}

// ---------------------------------------------------------------------------
// Grouped 3x3 conv (groups=256, 2 in / 2 out ch per group) -> d_out (pos path)
// out[b,t,c]: t==0 -> 0; else conv at (h,w)=((t-1)/32,(t-1)%32)
// ---------------------------------------------------------------------------
__global__ void conv_pos(const float* __restrict__ x,
                         const float* __restrict__ cw,
                         const float* __restrict__ cb,
                         float* __restrict__ out)
{
  const int idx = blockIdx.x * 256 + threadIdx.x;
  if (idx >= Bc * Tt * Cc) return;
  const int c = idx & 511;
  const int bt = idx >> 9;
  const int t = bt % Tt;
  const int b = bt / Tt;
  if (t == 0) { out[idx] = 0.f; return; }
  const int p = t - 1;
  const int hh = p >> 5, ww = p & 31;
  const float* wp = cw + c * 18;  // (2,3,3)
  const int ci = (c >> 1) << 1;   // group base input channel
  float s = cb[c];
  #pragma unroll
  for (int kh = 0; kh < 3; kh++) {
    const int h2 = hh + kh - 1;
    if ((unsigned)h2 > 31u) continue;
    #pragma unroll
    for (int kw = 0; kw < 3; kw++) {
      const int w2 = ww + kw - 1;
      if ((unsigned)w2 > 31u) continue;
      const float* xp = x + ((size_t)(b * Tt) + 1 + h2 * 32 + w2) * Cc + ci;
      s += xp[0] * wp[0 * 9 + kh * 3 + kw] + xp[1] * wp[1 * 9 + kh * 3 + kw];
    }
  }
  out[idx] = s;
}

// ---------------------------------------------------------------------------
// cat = [gr (bcast), x_summary] ; x_summary[b,i,:] = x_self[b, 4*i, :256]
// ---------------------------------------------------------------------------
__global__ void build_cat(const float* __restrict__ gr_cache,
                          const float* __restrict__ x_self,
                          float* __restrict__ cat)
{
  const int idx = blockIdx.x * 256 + threadIdx.x;
  if (idx >= Bc * Ll * 512) return;
  const int k = idx & 511;
  const int bi = idx >> 9;
  const int i = bi & 255;
  const int b = bi >> 8;
  float v;
  if (k < 256) v = gr_cache[i * 256 + k];
  else         v = x_self[((size_t)(b * Tt + 4 * i)) * Cc + (k - 256)];
  cat[idx] = v;
}

// cat[:, :256] = reset * gr  (in place; second half already x_summary)
__global__ void build_cat2(const float* __restrict__ gr_cache,
                           const float* __restrict__ reset,
                           float* __restrict__ cat)
{
  const int idx = blockIdx.x * 256 + threadIdx.x;
  if (idx >= Bc * Ll * 256) return;
  const int k = idx & 255;
  const int bi = idx >> 8;
  const int i = bi & 255;
  cat[(size_t)bi * 512 + k] = gr_cache[i * 256 + k] * reset[idx];
}

// ---------------------------------------------------------------------------
// LayerNorm(add_raw) * gamma + beta, then gr_new = z*ln + (1-z)*gr
// one block per (b,i) row of 256
// ---------------------------------------------------------------------------
__device__ inline float block_sum256(float v, float* red)
{
  #pragma unroll
  for (int o = 32; o >= 1; o >>= 1) v += __shfl_down(v, o);
  const int wid = threadIdx.x >> 6;
  if ((threadIdx.x & 63) == 0) red[wid] = v;
  __syncthreads();
  const float t = red[0] + red[1] + red[2] + red[3];
  __syncthreads();
  return t;
}

__global__ __launch_bounds__(256) void ln_gate(
    const float* __restrict__ add_raw, const float* __restrict__ z,
    const float* __restrict__ gr_cache, const float* __restrict__ gamma,
    const float* __restrict__ beta, float* __restrict__ gr_new)
{
  __shared__ float red[4];
  const int bi = blockIdx.x;  // 0..B*L-1
  const int i = bi & 255;
  const int c = threadIdx.x;
  const float v = add_raw[(size_t)bi * 256 + c];
  const float mu = block_sum256(v, red) * (1.f / 256.f);
  const float dv = v - mu;
  const float var = block_sum256(dv * dv, red) * (1.f / 256.f);
  const float nrm = dv * rsqrtf(var + 1e-5f) * gamma[c] + beta[c];
  const float zz = z[(size_t)bi * 256 + c];
  gr_new[(size_t)bi * 256 + c] = zz * nrm + (1.f - zz) * gr_cache[i * 256 + c];
}

// ---------------------------------------------------------------------------
// out += alpha_h * pad(x_mem) + (1-alpha_h) * x_self   (pos already in out)
// ---------------------------------------------------------------------------
__global__ void combine(const float* __restrict__ x_self,
                        const float* __restrict__ x_mem,
                        const float* __restrict__ lam,
                        float* __restrict__ out)
{
  const int idx = blockIdx.x * 256 + threadIdx.x;
  if (idx >= Bc * Tt * Cc) return;
  const int c = idx & 511;
  const int bt = idx >> 9;
  const int hh = c >> 6;
  const int dd = c & 63;
  const float alpha = 1.f / (1.f + __expf(-lam[hh]));
  const float mem = (dd < 32) ? x_mem[(size_t)bt * 256 + hh * 32 + dd] : 0.f;
  out[idx] += alpha * mem + (1.f - alpha) * x_self[idx];
}

// ---------------------------------------------------------------------------
extern "C" void kernel_launch(void* const* d_in, const int* in_sizes, int n_in,
                              void* d_out, int out_size, void* d_ws, size_t ws_size,
                              hipStream_t stream)
{
  const float* x        = (const float*)d_in[0];
  const float* gr_cache = (const float*)d_in[1];
  const float* Wq1 = (const float*)d_in[2];  const float* bq1 = (const float*)d_in[3];
  const float* Wk1 = (const float*)d_in[4];  const float* bk1 = (const float*)d_in[5];
  const float* Wv1 = (const float*)d_in[6];  const float* bv1 = (const float*)d_in[7];
  const float* Wo1 = (const float*)d_in[8];  const float* bo1 = (const float*)d_in[9];
  const float* Wq2 = (const float*)d_in[10]; const float* bq2 = (const float*)d_in[11];
  const float* Wk2 = (const float*)d_in[12]; const float* bk2 = (const float*)d_in[13];
  const float* Wv2 = (const float*)d_in[14]; const float* bv2 = (const float*)d_in[15];
  const float* Wo2 = (const float*)d_in[16]; const float* bo2 = (const float*)d_in[17];
  const float* Wr  = (const float*)d_in[18]; const float* br  = (const float*)d_in[19];
  const float* Wz  = (const float*)d_in[20]; const float* bz  = (const float*)d_in[21];
  const float* Wa  = (const float*)d_in[22]; const float* ba  = (const float*)d_in[23];
  const float* gamma = (const float*)d_in[24];
  const float* beta  = (const float*)d_in[25];
  const float* lam   = (const float*)d_in[26];
  const float* conv_w = (const float*)d_in[27];
  const float* conv_b = (const float*)d_in[28];
  float* out = (float*)d_out;

  const int M1 = Bc * Tt;       // 8200
  const int M2 = Bc * Ll;       // 2048
  const size_t BTC = (size_t)Bc * Tt * Cc;    // 4,198,400
  const size_t BTA = (size_t)Bc * Tt * CA;    // 2,099,200
  const size_t BLA = (size_t)Bc * Ll * CA;    // 524,288
  const size_t BL2 = (size_t)Bc * Ll * 512;   // 1,048,576

  float* ws = (float*)d_ws;
  // phase 1 buffers
  float* q1     = ws;
  float* k1     = q1 + BTC;
  float* v1     = k1 + BTC;
  float* att1   = v1 + BTC;
  float* x_self = att1 + BTC;   // survives to the end (offset 16.79M floats)
  // phase 2+ buffers reuse the q1/k1/v1/att1 region (all dead by then)
  float* cat     = ws;                 // B*L*512
  float* reset   = cat + BL2;          // B*L*256
  float* zg      = reset + BLA;
  float* add_raw = zg + BLA;
  float* gr_new  = add_raw + BLA;
  float* q2      = gr_new + BLA;       // B*T*256
  float* k2      = q2 + BTA;           // B*L*256
  float* v2      = k2 + BLA;
  float* att2    = v2 + BLA;           // B*T*256
  float* x_mem   = att2 + BTA;         // ends at 10.49M floats < att1 offset

  const dim3 blk(256);
  const dim3 gemm_g1(Cc / 64, (M1 + 63) / 64);   // N=512, M=8200
  const dim3 gemm_g2(CA / 64, (M2 + 63) / 64);   // N=256, M=2048
  const dim3 gemm_g3(CA / 64, (M1 + 63) / 64);   // N=256, M=8200
  const int ew_btc = (int)((BTC + 255) / 256);

  // pos path (independent) -> writes every element of d_out
  conv_pos<<<ew_btc, blk, 0, stream>>>(x, conv_w, conv_b, out);

  // MHA1
  gemm_bias<<<gemm_g1, blk, 0, stream>>>(x, Cc, Wq1, bq1, q1, M1, Cc, Cc, EP_NONE);
  gemm_bias<<<gemm_g1, blk, 0, stream>>>(x, Cc, Wk1, bk1, k1, M1, Cc, Cc, EP_NONE);
  gemm_bias<<<gemm_g1, blk, 0, stream>>>(x, Cc, Wv1, bv1, v1, M1, Cc, Cc, EP_NONE);
  attn_flash<64><<<dim3((Tt + 31) / 32, Bc * Hn), blk, 0, stream>>>(
      q1, k1, v1, att1, Tt, Tt, 0.125f, Tt * Cc, Tt * Cc);
  gemm_bias<<<gemm_g1, blk, 0, stream>>>(att1, Cc, Wo1, bo1, x_self, M1, Cc, Cc, EP_NONE);

  // GRU-style cache update
  build_cat<<<(int)((BL2 + 255) / 256), blk, 0, stream>>>(gr_cache, x_self, cat);
  gemm_bias<<<gemm_g2, blk, 0, stream>>>(cat, 512, Wr, br, reset, M2, CA, 512, EP_SIGMOID);
  gemm_bias<<<gemm_g2, blk, 0, stream>>>(cat, 512, Wz, bz, zg, M2, CA, 512, EP_SIGMOID);
  build_cat2<<<(int)((BLA + 255) / 256), blk, 0, stream>>>(gr_cache, reset, cat);
  gemm_bias<<<gemm_g2, blk, 0, stream>>>(cat, 512, Wa, ba, add_raw, M2, CA, 512, EP_GELU);
  ln_gate<<<M2, blk, 0, stream>>>(add_raw, zg, gr_cache, gamma, beta, gr_new);

  // MHA2 (q from x[:,:,:256], kv from gr_new)
  gemm_bias<<<gemm_g3, blk, 0, stream>>>(x, Cc, Wq2, bq2, q2, M1, CA, CA, EP_NONE);
  gemm_bias<<<gemm_g2, blk, 0, stream>>>(gr_new, CA, Wk2, bk2, k2, M2, CA, CA, EP_NONE);
  gemm_bias<<<gemm_g2, blk, 0, stream>>>(gr_new, CA, Wv2, bv2, v2, M2, CA, CA, EP_NONE);
  attn_flash<32><<<dim3((Tt + 31) / 32, Bc * Hn), blk, 0, stream>>>(
      q2, k2, v2, att2, Tt, Ll, 0.17677669529663689f, Tt * CA, Ll * CA);
  gemm_bias<<<gemm_g3, blk, 0, stream>>>(att2, CA, Wo2, bo2, x_mem, M1, CA, CA, EP_NONE);

  // final mix (pos already in out)
  combine<<<ew_btc, blk, 0, stream>>>(x_self, x_mem, lam, out);
}

// Round 2
// 555.091 us; speedup vs baseline: 2.6918x; 2.6918x over previous
//
#include <hip/hip_runtime.h>
#include <math.h>

typedef unsigned short u16;
typedef unsigned int u32;
typedef __attribute__((ext_vector_type(8))) short short8;
typedef __attribute__((ext_vector_type(4))) short short4v;
typedef __attribute__((ext_vector_type(4))) float f32x4;

// Problem constants
constexpr int Bc = 8;
constexpr int Tt = 1025;
constexpr int Cc = 512;
constexpr int Hn = 8;
constexpr int CA = 256;
constexpr int Ll = 256;

__device__ __forceinline__ u16 f2bf(float f) {
  u32 u = __builtin_bit_cast(u32, f);
  u = (u + 0x7FFFu + ((u >> 16) & 1u)) >> 16;
  return (u16)u;
}
__device__ __forceinline__ float bf2f(u16 h) {
  u32 u = ((u32)h) << 16;
  return __builtin_bit_cast(float, u);
}

// ---------------------------------------------------------------------------
// Weight cast+transpose: W[K][N] fp32 -> Wt[N][K] bf16. One y-block per weight.
// ---------------------------------------------------------------------------
struct WC { const float* s; u16* d; int N; int tot; int kshift; };
struct WCP { WC w[11]; };

__global__ void wcast_k(WCP p) {
  const WC a = p.w[blockIdx.y];
  const int kmask = (1 << a.kshift) - 1;
  for (int idx = blockIdx.x * 256 + threadIdx.x; idx < a.tot; idx += gridDim.x * 256) {
    const int k = idx & kmask;
    const int n = idx >> a.kshift;
    a.d[idx] = f2bf(a.s[(size_t)k * a.N + n]);
  }
}

__global__ void xcast_k(const float* __restrict__ x, u16* __restrict__ xb, int n) {
  const int i = blockIdx.x * 256 + threadIdx.x;
  if (i < n) xb[i] = f2bf(x[i]);
}

// ---------------------------------------------------------------------------
// bf16 MFMA GEMM: C[M,N] = A[M,K](lda) @ W + bias.  Wt is W^T = [N][K] bf16.
// 128x128 tile, BK=32, 256 threads = 4 waves, each wave 64x64 (4x4 of 16x16).
// OUTBF: 1 -> bf16 out, 0 -> fp32 out.  ACT: 0 none, 1 sigmoid, 2 gelu.
// ---------------------------------------------------------------------------
enum { EP_NONE = 0, EP_SIGMOID = 1, EP_GELU = 2 };

template <int OUTBF, int ACT>
__global__ __launch_bounds__(256) void gemm_mfma(
    const u16* __restrict__ A, int lda,
    const u16* __restrict__ Wt,
    const float* __restrict__ bias,
    void* __restrict__ Cout,
    int M, int N, int K)
{
  __shared__ u16 As[128][32];
  __shared__ u16 Bs[128][32];
  const int tid = threadIdx.x;
  const int m0 = blockIdx.y * 128, n0 = blockIdx.x * 128;
  const int ln = tid & 15, quad = (tid >> 4) & 3, wv = tid >> 6;
  const int wm = (wv & 1) * 64, wn = (wv >> 1) * 64;
  const int sr = tid >> 1;          // staging row 0..127
  const int sk = (tid & 1) * 16;    // staging k offset

  f32x4 zf = {0.f, 0.f, 0.f, 0.f};
  f32x4 acc[4][4];
  #pragma unroll
  for (int i = 0; i < 4; i++)
    #pragma unroll
    for (int j = 0; j < 4; j++) acc[i][j] = zf;

  const short8 z8 = {0, 0, 0, 0, 0, 0, 0, 0};

  for (int k0 = 0; k0 < K; k0 += 32) {
    const int gm = m0 + sr;
    short8 a0 = z8, a1 = z8;
    if (gm < M) {
      const u16* p = A + (size_t)gm * lda + k0 + sk;
      a0 = *(const short8*)p;
      a1 = *(const short8*)(p + 8);
    }
    *(short8*)&As[sr][sk] = a0;
    *(short8*)&As[sr][sk + 8] = a1;
    {
      const u16* q = Wt + (size_t)(n0 + sr) * K + k0 + sk;
      *(short8*)&Bs[sr][sk] = *(const short8*)q;
      *(short8*)&Bs[sr][sk + 8] = *(const short8*)(q + 8);
    }
    __syncthreads();

    short8 af[4], bf[4];
    #pragma unroll
    for (int i = 0; i < 4; i++) af[i] = *(const short8*)&As[wm + i * 16 + ln][quad * 8];
    #pragma unroll
    for (int j = 0; j < 4; j++) bf[j] = *(const short8*)&Bs[wn + j * 16 + ln][quad * 8];
    #pragma unroll
    for (int i = 0; i < 4; i++)
      #pragma unroll
      for (int j = 0; j < 4; j++)
        acc[i][j] = __builtin_amdgcn_mfma_f32_16x16x32_bf16(af[i], bf[j], acc[i][j], 0, 0, 0);
    __syncthreads();
  }

  float bj[4];
  #pragma unroll
  for (int j = 0; j < 4; j++) bj[j] = bias[n0 + wn + j * 16 + ln];

  #pragma unroll
  for (int i = 0; i < 4; i++) {
    #pragma unroll
    for (int r = 0; r < 4; r++) {
      const int gm = m0 + wm + i * 16 + quad * 4 + r;
      if (gm >= M) continue;
      #pragma unroll
      for (int j = 0; j < 4; j++) {
        float v = acc[i][j][r] + bj[j];
        if (ACT == EP_SIGMOID)   v = 1.f / (1.f + __expf(-v));
        else if (ACT == EP_GELU) v = 0.5f * v * (1.f + erff(v * 0.70710678118654752f));
        const size_t off = (size_t)gm * N + n0 + wn + j * 16 + ln;
        if (OUTBF) ((u16*)Cout)[off] = f2bf(v);
        else       ((float*)Cout)[off] = v;
      }
    }
  }
}

// ---------------------------------------------------------------------------
// MFMA flash attention (bf16 in/out, fp32 softmax+accum).
// Block: 256 thr = 4 waves; wave handles 32 q rows; KT=32 keys/iter in LDS.
// Scores: S = Q·K^T via mfma(A=Qfrag, B=Kfrag).  PV: O = P·V via
// mfma(A=Pfrag from LDS round-trip, B=Vt frag).  C-layout rows == softmax rows.
// ---------------------------------------------------------------------------
template <int DH>
__global__ __launch_bounds__(256) void attn_mfma(
    const u16* __restrict__ Q, const u16* __restrict__ Kp,
    const u16* __restrict__ Vp, u16* __restrict__ O,
    int Tq, int Tk, float scale, int qbs, int kbs)
{
  constexpr int RS = Hn * DH;        // row stride (els)
  constexpr int KSTR = DH + 8;       // Ks stride: 72 / 40 (16B-aligned b128, bank-uniform)
  constexpr int NC32 = DH / 32;      // score K-chunks
  constexpr int NC16 = DH / 16;      // PV d-chunks

  __shared__ u16 Ks[32][KSTR];
  __shared__ u16 Vt[DH][56];         // V transposed: Vt[d][k], stride 56
  __shared__ u16 Pb[4][32][40];      // per-wave P tile [qrow][k], stride 40

  const int b = blockIdx.y >> 3, h = blockIdx.y & 7;
  const int q0 = blockIdx.x * 128;
  const int tid = threadIdx.x;
  const int wv = tid >> 6;
  const int lane = tid & 63;
  const int ln = lane & 15, quad = lane >> 4;

  const u16* Qb = Q + (size_t)b * qbs + h * DH;
  const u16* Kb = Kp + (size_t)b * kbs + h * DH;
  const u16* Vb = Vp + (size_t)b * kbs + h * DH;
  u16* Ob = O + (size_t)b * qbs + h * DH;

  const short8 z8 = {0, 0, 0, 0, 0, 0, 0, 0};
  const f32x4 zf = {0.f, 0.f, 0.f, 0.f};

  // preload Q fragments (invariant over K loop)
  short8 qf[2][NC32];
  #pragma unroll
  for (int qs = 0; qs < 2; qs++) {
    const int gq = q0 + wv * 32 + qs * 16 + ln;
    #pragma unroll
    for (int c = 0; c < NC32; c++) {
      if (gq < Tq) qf[qs][c] = *(const short8*)(Qb + (size_t)gq * RS + c * 32 + quad * 8);
      else         qf[qs][c] = z8;
    }
  }

  f32x4 oacc[2][NC16];
  float mrow[2][4], lrow[2][4];
  #pragma unroll
  for (int qs = 0; qs < 2; qs++) {
    #pragma unroll
    for (int c = 0; c < NC16; c++) oacc[qs][c] = zf;
    #pragma unroll
    for (int r = 0; r < 4; r++) { mrow[qs][r] = -1e30f; lrow[qs][r] = 0.f; }
  }

  // staging index maps
  const int skk = tid >> 3;                    // K row 0..31
  const int sd0 = (tid & 7) * (DH / 8);        // K col chunk
  const int vd0 = (tid & 15) * (DH == 64 ? 4 : 2);
  const int vk  = ((tid >> 4) & 15) * 2;       // even key pair

  const int nit = (Tk + 31) >> 5;
  for (int it = 0; it < nit; it++) {
    const int k0 = it << 5;
    __syncthreads();
    // ---- stage K tile ----
    {
      const int gk = k0 + skk;
      if (DH == 64) {
        short8 kv = z8;
        if (gk < Tk) kv = *(const short8*)(Kb + (size_t)gk * RS + sd0);
        *(short8*)&Ks[skk][sd0] = kv;
      } else {
        short4v kv = {0, 0, 0, 0};
        if (gk < Tk) kv = *(const short4v*)(Kb + (size_t)gk * RS + sd0);
        *(short4v*)&Ks[skk][sd0] = kv;
      }
    }
    // ---- stage V tile transposed (pair-of-keys trick -> ushort2 writes) ----
    {
      const int gk0 = k0 + vk, gk1 = gk0 + 1;
      const int nd = (DH == 64 ? 4 : 2);
      u16 va[4] = {0, 0, 0, 0}, vb2[4] = {0, 0, 0, 0};
      if (gk0 < Tk) {
        const u16* p = Vb + (size_t)gk0 * RS + vd0;
        for (int i = 0; i < nd; i++) va[i] = p[i];
      }
      if (gk1 < Tk) {
        const u16* p = Vb + (size_t)gk1 * RS + vd0;
        for (int i = 0; i < nd; i++) vb2[i] = p[i];
      }
      for (int i = 0; i < nd; i++) {
        ushort2 w2; w2.x = va[i]; w2.y = vb2[i];
        *(ushort2*)&Vt[vd0 + i][vk] = w2;
      }
    }
    __syncthreads();

    // ---- scores: 2 qsub x 2 kcol tiles of 16x16 ----
    short8 kf[2][NC32];
    #pragma unroll
    for (int kc = 0; kc < 2; kc++)
      #pragma unroll
      for (int c = 0; c < NC32; c++)
        kf[kc][c] = *(const short8*)&Ks[kc * 16 + ln][c * 32 + quad * 8];

    f32x4 sc[2][2];
    #pragma unroll
    for (int qs = 0; qs < 2; qs++)
      #pragma unroll
      for (int kc = 0; kc < 2; kc++) {
        f32x4 a = zf;
        #pragma unroll
        for (int c = 0; c < NC32; c++)
          a = __builtin_amdgcn_mfma_f32_16x16x32_bf16(qf[qs][c], kf[kc][c], a, 0, 0, 0);
        sc[qs][kc] = a;
      }

    // ---- online softmax (rows = quad*4+r, cols = kcol*16+ln) ----
    const bool kok0 = (k0 + ln) < Tk;
    const bool kok1 = (k0 + 16 + ln) < Tk;
    #pragma unroll
    for (int qs = 0; qs < 2; qs++) {
      float al[4];
      #pragma unroll
      for (int r = 0; r < 4; r++) {
        float v0 = kok0 ? sc[qs][0][r] * scale : -1e30f;
        float v1 = kok1 ? sc[qs][1][r] * scale : -1e30f;
        float mx = fmaxf(v0, v1);
        mx = fmaxf(mx, __shfl_xor(mx, 1));
        mx = fmaxf(mx, __shfl_xor(mx, 2));
        mx = fmaxf(mx, __shfl_xor(mx, 4));
        mx = fmaxf(mx, __shfl_xor(mx, 8));
        const float mo = mrow[qs][r];
        const float mn = fmaxf(mo, mx);
        const float p0 = __expf(v0 - mn);
        const float p1 = __expf(v1 - mn);
        float rs = p0 + p1;
        rs += __shfl_xor(rs, 1);
        rs += __shfl_xor(rs, 2);
        rs += __shfl_xor(rs, 4);
        rs += __shfl_xor(rs, 8);
        al[r] = __expf(mo - mn);
        lrow[qs][r] = lrow[qs][r] * al[r] + rs;
        mrow[qs][r] = mn;
        const int qloc = qs * 16 + quad * 4 + r;
        Pb[wv][qloc][ln] = f2bf(p0);
        Pb[wv][qloc][16 + ln] = f2bf(p1);
      }
      #pragma unroll
      for (int c = 0; c < NC16; c++)
        #pragma unroll
        for (int r = 0; r < 4; r++) oacc[qs][c][r] *= al[r];
    }
    __syncthreads();

    // ---- PV: O += P · V ----
    short8 pf[2];
    #pragma unroll
    for (int qs = 0; qs < 2; qs++)
      pf[qs] = *(const short8*)&Pb[wv][qs * 16 + ln][quad * 8];
    #pragma unroll
    for (int c = 0; c < NC16; c++) {
      const short8 vf = *(const short8*)&Vt[c * 16 + ln][quad * 8];
      #pragma unroll
      for (int qs = 0; qs < 2; qs++)
        oacc[qs][c] = __builtin_amdgcn_mfma_f32_16x16x32_bf16(pf[qs], vf, oacc[qs][c], 0, 0, 0);
    }
  }

  // ---- epilogue: divide by l, store bf16 ----
  #pragma unroll
  for (int qs = 0; qs < 2; qs++) {
    #pragma unroll
    for (int r = 0; r < 4; r++) {
      const int gq = q0 + wv * 32 + qs * 16 + quad * 4 + r;
      if (gq >= Tq) continue;
      const float inv = 1.f / lrow[qs][r];
      #pragma unroll
      for (int c = 0; c < NC16; c++)
        Ob[(size_t)gq * RS + c * 16 + ln] = f2bf(oacc[qs][c][r] * inv);
    }
  }
}

// ---------------------------------------------------------------------------
// Grouped 3x3 conv (groups=256, 2ch/group) -> d_out (pos path), fp32
// ---------------------------------------------------------------------------
__global__ void conv_pos(const float* __restrict__ x,
                         const float* __restrict__ cw,
                         const float* __restrict__ cb,
                         float* __restrict__ out)
{
  const int idx = blockIdx.x * 256 + threadIdx.x;
  if (idx >= Bc * Tt * Cc) return;
  const int c = idx & 511;
  const int bt = idx >> 9;
  const int t = bt % Tt;
  const int b = bt / Tt;
  if (t == 0) { out[idx] = 0.f; return; }
  const int p = t - 1;
  const int hh = p >> 5, ww = p & 31;
  const float* wp = cw + c * 18;
  const int ci = (c >> 1) << 1;
  float s = cb[c];
  #pragma unroll
  for (int kh = 0; kh < 3; kh++) {
    const int h2 = hh + kh - 1;
    if ((unsigned)h2 > 31u) continue;
    #pragma unroll
    for (int kw = 0; kw < 3; kw++) {
      const int w2 = ww + kw - 1;
      if ((unsigned)w2 > 31u) continue;
      const float* xp = x + ((size_t)(b * Tt) + 1 + h2 * 32 + w2) * Cc + ci;
      s += xp[0] * wp[0 * 9 + kh * 3 + kw] + xp[1] * wp[1 * 9 + kh * 3 + kw];
    }
  }
  out[idx] = s;
}

// cat = [gr (bcast) | x_summary] bf16 ; x_summary[b,i,:] = x_self[b, 4*i, :256]
__global__ void build_cat(const float* __restrict__ gr_cache,
                          const float* __restrict__ x_self,
                          u16* __restrict__ cat)
{
  const int idx = blockIdx.x * 256 + threadIdx.x;
  if (idx >= Bc * Ll * 512) return;
  const int k = idx & 511;
  const int bi = idx >> 9;
  const int i = bi & 255;
  const int b = bi >> 8;
  float v;
  if (k < 256) v = gr_cache[i * 256 + k];
  else         v = x_self[((size_t)(b * Tt + 4 * i)) * Cc + (k - 256)];
  cat[idx] = f2bf(v);
}

// cat[:, :256] = bf16(reset * gr)   (in place)
__global__ void build_cat2(const float* __restrict__ gr_cache,
                           const float* __restrict__ reset,
                           u16* __restrict__ cat)
{
  const int idx = blockIdx.x * 256 + threadIdx.x;
  if (idx >= Bc * Ll * 256) return;
  const int k = idx & 255;
  const int bi = idx >> 8;
  const int i = bi & 255;
  cat[(size_t)bi * 512 + k] = f2bf(gr_cache[i * 256 + k] * reset[idx]);
}

// LayerNorm + gate -> gr_new bf16
__device__ inline float block_sum256(float v, float* red)
{
  #pragma unroll
  for (int o = 32; o >= 1; o >>= 1) v += __shfl_down(v, o);
  const int wid = threadIdx.x >> 6;
  if ((threadIdx.x & 63) == 0) red[wid] = v;
  __syncthreads();
  const float t = red[0] + red[1] + red[2] + red[3];
  __syncthreads();
  return t;
}

__global__ __launch_bounds__(256) void ln_gate(
    const float* __restrict__ add_raw, const float* __restrict__ z,
    const float* __restrict__ gr_cache, const float* __restrict__ gamma,
    const float* __restrict__ beta, u16* __restrict__ gr_new)
{
  __shared__ float red[4];
  const int bi = blockIdx.x;
  const int i = bi & 255;
  const int c = threadIdx.x;
  const float v = add_raw[(size_t)bi * 256 + c];
  const float mu = block_sum256(v, red) * (1.f / 256.f);
  const float dv = v - mu;
  const float var = block_sum256(dv * dv, red) * (1.f / 256.f);
  const float nrm = dv * rsqrtf(var + 1e-5f) * gamma[c] + beta[c];
  const float zz = z[(size_t)bi * 256 + c];
  gr_new[(size_t)bi * 256 + c] = f2bf(zz * nrm + (1.f - zz) * gr_cache[i * 256 + c]);
}

// out += alpha_h * pad(x_mem) + (1-alpha_h) * x_self
__global__ void combine(const float* __restrict__ x_self,
                        const float* __restrict__ x_mem,
                        const float* __restrict__ lam,
                        float* __restrict__ out)
{
  const int idx = blockIdx.x * 256 + threadIdx.x;
  if (idx >= Bc * Tt * Cc) return;
  const int c = idx & 511;
  const int bt = idx >> 9;
  const int hh = c >> 6;
  const int dd = c & 63;
  const float alpha = 1.f / (1.f + __expf(-lam[hh]));
  const float mem = (dd < 32) ? x_mem[(size_t)bt * 256 + hh * 32 + dd] : 0.f;
  out[idx] += alpha * mem + (1.f - alpha) * x_self[idx];
}

// ---------------------------------------------------------------------------
extern "C" void kernel_launch(void* const* d_in, const int* in_sizes, int n_in,
                              void* d_out, int out_size, void* d_ws, size_t ws_size,
                              hipStream_t stream)
{
  const float* x        = (const float*)d_in[0];
  const float* gr_cache = (const float*)d_in[1];
  const float* Wq1 = (const float*)d_in[2];  const float* bq1 = (const float*)d_in[3];
  const float* Wk1 = (const float*)d_in[4];  const float* bk1 = (const float*)d_in[5];
  const float* Wv1 = (const float*)d_in[6];  const float* bv1 = (const float*)d_in[7];
  const float* Wo1 = (const float*)d_in[8];  const float* bo1 = (const float*)d_in[9];
  const float* Wq2 = (const float*)d_in[10]; const float* bq2 = (const float*)d_in[11];
  const float* Wk2 = (const float*)d_in[12]; const float* bk2 = (const float*)d_in[13];
  const float* Wv2 = (const float*)d_in[14]; const float* bv2 = (const float*)d_in[15];
  const float* Wo2 = (const float*)d_in[16]; const float* bo2 = (const float*)d_in[17];
  const float* Wr  = (const float*)d_in[18]; const float* br  = (const float*)d_in[19];
  const float* Wz  = (const float*)d_in[20]; const float* bz  = (const float*)d_in[21];
  const float* Wa  = (const float*)d_in[22]; const float* ba  = (const float*)d_in[23];
  const float* gamma = (const float*)d_in[24];
  const float* beta  = (const float*)d_in[25];
  const float* lam   = (const float*)d_in[26];
  const float* conv_w = (const float*)d_in[27];
  const float* conv_b = (const float*)d_in[28];
  float* out = (float*)d_out;

  const int M1 = Bc * Tt;       // 8200
  const int M2 = Bc * Ll;       // 2048
  const size_t BTC = (size_t)Bc * Tt * Cc;    // 4,198,400
  const size_t BTA = (size_t)Bc * Tt * CA;
  const size_t BLA = (size_t)Bc * Ll * CA;
  const size_t BL2 = (size_t)Bc * Ll * 512;

  char* W = (char*)d_ws;
  // phase-1 layout (bytes)
  u16*   xb     = (u16*)(W + 0);                       // 8,396,800 B
  u16*   q1     = (u16*)(W + 8396800);
  u16*   k1     = (u16*)(W + 16793600);
  u16*   v1     = (u16*)(W + 25190400);
  u16*   att1   = (u16*)(W + 33587200);
  float* x_self = (float*)(W + 41984000);              // 16,793,600 B
  u16*   wtb    = (u16*)(W + 58777600);                // 3,407,872 B, end 62,185,472
  // phase-2 overlay (q1/k1/v1 region; all writes happen after o-proj1)
  u16*   cat    = (u16*)(W + 8396800);                 // 2,097,152
  float* rg     = (float*)(W + 10493952);              // 2,097,152
  float* zg     = (float*)(W + 12591104);
  float* addr_  = (float*)(W + 14688256);
  u16*   gr_new = (u16*)(W + 16785408);                // 1,048,576
  u16*   k2     = (u16*)(W + 17833984);
  u16*   v2     = (u16*)(W + 18882560);
  u16*   q2     = (u16*)(W + 19931136);                // 4,198,400
  u16*   att2   = (u16*)(W + 24129536);                // 4,198,400
  float* x_mem  = (float*)(W + 28327936);              // 8,396,800 (overlaps dead att1)

  // Wt sub-offsets (elements)
  u16* Wq1t = wtb + 0;       u16* Wk1t = wtb + 262144;  u16* Wv1t = wtb + 524288;
  u16* Wo1t = wtb + 786432;  u16* Wrt  = wtb + 1048576; u16* Wzt  = wtb + 1179648;
  u16* Wat  = wtb + 1310720; u16* Wq2t = wtb + 1441792; u16* Wk2t = wtb + 1507328;
  u16* Wv2t = wtb + 1572864; u16* Wo2t = wtb + 1638400;

  const dim3 blk(256);
  const int ew_btc = (int)((BTC + 255) / 256);

  // ---- casts ----
  {
    WCP p;
    const float* ws_[11] = {Wq1, Wk1, Wv1, Wo1, Wr, Wz, Wa, Wq2, Wk2, Wv2, Wo2};
    u16* wd_[11] = {Wq1t, Wk1t, Wv1t, Wo1t, Wrt, Wzt, Wat, Wq2t, Wk2t, Wv2t, Wo2t};
    const int Kk[11] = {512,512,512,512,512,512,512,256,256,256,256};
    const int Nn[11] = {512,512,512,512,256,256,256,256,256,256,256};
    for (int i = 0; i < 11; i++) {
      p.w[i].s = ws_[i]; p.w[i].d = wd_[i]; p.w[i].N = Nn[i];
      p.w[i].tot = Kk[i] * Nn[i];
      p.w[i].kshift = (Kk[i] == 512) ? 9 : 8;
    }
    wcast_k<<<dim3(64, 11), blk, 0, stream>>>(p);
  }
  xcast_k<<<ew_btc, blk, 0, stream>>>(x, xb, (int)BTC);

  // pos path -> d_out
  conv_pos<<<ew_btc, blk, 0, stream>>>(x, conv_w, conv_b, out);

  // ---- MHA1 ----
  const dim3 g512(4, 65), g256m1(2, 65), g256m2(2, 16);
  gemm_mfma<1, EP_NONE><<<g512, blk, 0, stream>>>(xb, 512, Wq1t, bq1, q1, M1, 512, 512);
  gemm_mfma<1, EP_NONE><<<g512, blk, 0, stream>>>(xb, 512, Wk1t, bk1, k1, M1, 512, 512);
  gemm_mfma<1, EP_NONE><<<g512, blk, 0, stream>>>(xb, 512, Wv1t, bv1, v1, M1, 512, 512);
  attn_mfma<64><<<dim3(9, 64), blk, 0, stream>>>(q1, k1, v1, att1, Tt, Tt, 0.125f,
                                                 Tt * 512, Tt * 512);
  gemm_mfma<0, EP_NONE><<<g512, blk, 0, stream>>>(att1, 512, Wo1t, bo1, x_self, M1, 512, 512);

  // ---- GRU cache update ----
  build_cat<<<(int)((BL2 + 255) / 256), blk, 0, stream>>>(gr_cache, x_self, cat);
  gemm_mfma<0, EP_SIGMOID><<<g256m2, blk, 0, stream>>>(cat, 512, Wrt, br, rg, M2, 256, 512);
  gemm_mfma<0, EP_SIGMOID><<<g256m2, blk, 0, stream>>>(cat, 512, Wzt, bz, zg, M2, 256, 512);
  build_cat2<<<(int)((BLA + 255) / 256), blk, 0, stream>>>(gr_cache, rg, cat);
  gemm_mfma<0, EP_GELU><<<g256m2, blk, 0, stream>>>(cat, 512, Wat, ba, addr_, M2, 256, 512);
  ln_gate<<<M2, blk, 0, stream>>>(addr_, zg, gr_cache, gamma, beta, gr_new);

  // ---- MHA2 ----
  gemm_mfma<1, EP_NONE><<<g256m1, blk, 0, stream>>>(xb, 512, Wq2t, bq2, q2, M1, 256, 256);
  gemm_mfma<1, EP_NONE><<<g256m2, blk, 0, stream>>>(gr_new, 256, Wk2t, bk2, k2, M2, 256, 256);
  gemm_mfma<1, EP_NONE><<<g256m2, blk, 0, stream>>>(gr_new, 256, Wv2t, bv2, v2, M2, 256, 256);
  attn_mfma<32><<<dim3(9, 64), blk, 0, stream>>>(q2, k2, v2, att2, Tt, Ll,
                                                 0.17677669529663689f, Tt * 256, Ll * 256);
  gemm_mfma<0, EP_NONE><<<g256m1, blk, 0, stream>>>(att2, 256, Wo2t, bo2, x_mem, M1, 256, 256);

  // final mix
  combine<<<ew_btc, blk, 0, stream>>>(x_self, x_mem, lam, out);
}

// Round 4
// 475.750 us; speedup vs baseline: 3.1407x; 1.1668x over previous
//
#include <hip/hip_runtime.h>
#include <math.h>

typedef unsigned short u16;
typedef unsigned int u32;
typedef __attribute__((ext_vector_type(8))) short short8;
typedef __attribute__((ext_vector_type(4))) short short4v;
typedef __attribute__((ext_vector_type(4))) float f32x4;

// Problem constants
constexpr int Bc = 8;
constexpr int Tt = 1025;
constexpr int Cc = 512;
constexpr int Hn = 8;
constexpr int CA = 256;
constexpr int Ll = 256;

__device__ __forceinline__ u16 f2bf(float f) {
  u32 u = __builtin_bit_cast(u32, f);
  u = (u + 0x7FFFu + ((u >> 16) & 1u)) >> 16;
  return (u16)u;
}
// pack two fp32 -> bf16x2 word (RNE)
__device__ __forceinline__ u32 pack2(float lo, float hi) {
  return (u32)f2bf(lo) | ((u32)f2bf(hi) << 16);
}

// ---------------------------------------------------------------------------
// Weight cast+transpose: W[K][N] fp32 -> Wt[N][K] bf16.
// ---------------------------------------------------------------------------
struct WC { const float* s; u16* d; int N; int tot; int kshift; };
struct WCP { WC w[11]; };

__global__ void wcast_k(WCP p) {
  const WC a = p.w[blockIdx.y];
  const int kmask = (1 << a.kshift) - 1;
  for (int idx = blockIdx.x * 256 + threadIdx.x; idx < a.tot; idx += gridDim.x * 256) {
    const int k = idx & kmask;
    const int n = idx >> a.kshift;
    a.d[idx] = f2bf(a.s[(size_t)k * a.N + n]);
  }
}

__global__ void xcast_k(const float* __restrict__ x, u16* __restrict__ xb, int n) {
  const int i = blockIdx.x * 256 + threadIdx.x;
  if (i < n) xb[i] = f2bf(x[i]);
}

// ---------------------------------------------------------------------------
// bf16 MFMA GEMM: C[M,N] = ((A[M,K] @ W) + bias) * oscale, epilogue act.
// 128x128 tile, BK=32, 256 thr = 4 waves, each 64x64 (4x4 of 16x16x32).
// ---------------------------------------------------------------------------
enum { EP_NONE = 0, EP_SIGMOID = 1, EP_GELU = 2 };

template <int OUTBF, int ACT>
__global__ __launch_bounds__(256) void gemm_mfma(
    const u16* __restrict__ A, int lda,
    const u16* __restrict__ Wt,
    const float* __restrict__ bias,
    void* __restrict__ Cout,
    int M, int N, int K, float oscale)
{
  __shared__ u16 As[128][32];
  __shared__ u16 Bs[128][32];
  const int tid = threadIdx.x;
  const int m0 = blockIdx.y * 128, n0 = blockIdx.x * 128;
  const int ln = tid & 15, quad = (tid >> 4) & 3, wv = tid >> 6;
  const int wm = (wv & 1) * 64, wn = (wv >> 1) * 64;
  const int sr = tid >> 1;
  const int sk = (tid & 1) * 16;

  f32x4 zf = {0.f, 0.f, 0.f, 0.f};
  f32x4 acc[4][4];
  #pragma unroll
  for (int i = 0; i < 4; i++)
    #pragma unroll
    for (int j = 0; j < 4; j++) acc[i][j] = zf;

  const short8 z8 = {0, 0, 0, 0, 0, 0, 0, 0};

  for (int k0 = 0; k0 < K; k0 += 32) {
    const int gm = m0 + sr;
    short8 a0 = z8, a1 = z8;
    if (gm < M) {
      const u16* p = A + (size_t)gm * lda + k0 + sk;
      a0 = *(const short8*)p;
      a1 = *(const short8*)(p + 8);
    }
    *(short8*)&As[sr][sk] = a0;
    *(short8*)&As[sr][sk + 8] = a1;
    {
      const u16* q = Wt + (size_t)(n0 + sr) * K + k0 + sk;
      *(short8*)&Bs[sr][sk] = *(const short8*)q;
      *(short8*)&Bs[sr][sk + 8] = *(const short8*)(q + 8);
    }
    __syncthreads();

    short8 af[4], bf[4];
    #pragma unroll
    for (int i = 0; i < 4; i++) af[i] = *(const short8*)&As[wm + i * 16 + ln][quad * 8];
    #pragma unroll
    for (int j = 0; j < 4; j++) bf[j] = *(const short8*)&Bs[wn + j * 16 + ln][quad * 8];
    #pragma unroll
    for (int i = 0; i < 4; i++)
      #pragma unroll
      for (int j = 0; j < 4; j++)
        acc[i][j] = __builtin_amdgcn_mfma_f32_16x16x32_bf16(af[i], bf[j], acc[i][j], 0, 0, 0);
    __syncthreads();
  }

  float bj[4];
  #pragma unroll
  for (int j = 0; j < 4; j++) bj[j] = bias[n0 + wn + j * 16 + ln];

  #pragma unroll
  for (int i = 0; i < 4; i++) {
    #pragma unroll
    for (int r = 0; r < 4; r++) {
      const int gm = m0 + wm + i * 16 + quad * 4 + r;
      if (gm >= M) continue;
      #pragma unroll
      for (int j = 0; j < 4; j++) {
        float v = (acc[i][j][r] + bj[j]) * oscale;
        if (ACT == EP_SIGMOID)   v = 1.f / (1.f + __expf(-v));
        else if (ACT == EP_GELU) v = 0.5f * v * (1.f + erff(v * 0.70710678118654752f));
        const size_t off = (size_t)gm * N + n0 + wn + j * 16 + ln;
        if (OUTBF) ((u16*)Cout)[off] = f2bf(v);
        else       ((float*)Cout)[off] = v;
      }
    }
  }
}

// ---------------------------------------------------------------------------
// MFMA flash attention v3.  Block = 128 thr = 2 waves, each wave 32 q rows.
// Scores computed TRANSPOSED (S^T = K·Q^T): C rows = keys (quad*4+r),
// cols = q (ln)  ->  softmax needs NO cross-lane ops in the loop.
// No-max softmax: p = exp(s) (scale pre-folded into Q), l accumulated
// per-lane, reduced across quads once in the epilogue.
// P^T C-layout writes 4 contiguous keys/lane -> ds_write_b64 into per-wave
// Pb[q][key]; PV = full-rate 16x16x32: A = P (b128), B = V^T (b128).
// ---------------------------------------------------------------------------
template <int DH>
__global__ __launch_bounds__(128) void attn_mfma(
    const u16* __restrict__ Qp, const u16* __restrict__ Kp,
    const u16* __restrict__ Vp, u16* __restrict__ Op,
    int Tq, int Tk, int qbs, int kbs)
{
  constexpr int RS = Hn * DH;     // row stride (elements)
  constexpr int KS = DH + 8;      // Ks stride
  constexpr int VS = 40;          // Vt / Pb key-stride (32 keys + 8 pad, 16B-aligned)
  constexpr int NC = DH / 32;     // d-chunks for scores
  constexpr int NM = DH / 16;     // d-tiles for output

  __shared__ u16 Ks[32][KS];      // K tile [key][d]
  __shared__ u16 Vt[DH][VS];      // V^T tile [d][key]
  __shared__ u16 Pb[2][32][VS];   // per-wave P [q][key]

  const int b = blockIdx.y >> 3, h = blockIdx.y & 7;
  const int q0 = blockIdx.x * 64;
  const int tid = threadIdx.x;
  const int wv = tid >> 6;
  const int lane = tid & 63;
  const int ln = lane & 15, quad = lane >> 4;

  const u16* Qb = Qp + (size_t)b * qbs + h * DH;
  const u16* Kb = Kp + (size_t)b * kbs + h * DH;
  const u16* Vb = Vp + (size_t)b * kbs + h * DH;
  u16* Ob = Op + (size_t)b * qbs + h * DH;

  const short8 z8 = {0, 0, 0, 0, 0, 0, 0, 0};
  const f32x4 zf = {0.f, 0.f, 0.f, 0.f};

  // Q fragments: content Q[q=ln][d=c*32+quad*8+j] (B-operand = Q^T)
  short8 qf[2][NC];
  #pragma unroll
  for (int qs = 0; qs < 2; qs++) {
    const int gq = q0 + wv * 32 + qs * 16 + ln;
    #pragma unroll
    for (int c = 0; c < NC; c++) {
      if (gq < Tq) qf[qs][c] = *(const short8*)(Qb + (size_t)gq * RS + c * 32 + quad * 8);
      else         qf[qs][c] = z8;
    }
  }

  f32x4 oacc[2][NM];
  float lsum[2] = {0.f, 0.f};
  #pragma unroll
  for (int qs = 0; qs < 2; qs++)
    #pragma unroll
    for (int c = 0; c < NM; c++) oacc[qs][c] = zf;

  // staging maps
  const int skk = tid >> 2;                 // K row 0..31
  const int sd0 = (tid & 3) * (DH / 4);     // K col chunk
  const int vd0 = (tid & 15) * (DH / 16);   // V d chunk (4 or 2 cols)
  const int vk  = (tid >> 4) * 4;           // V key group (4 rows)

  const int nit = (Tk + 31) >> 5;
  for (int it = 0; it < nit; it++) {
    const int k0 = it << 5;
    __syncthreads();
    // ---- stage K [key][d] ----
    {
      const int gk = k0 + skk;
      if (DH == 64) {
        short8 a = z8, b2 = z8;
        if (gk < Tk) {
          const u16* p = Kb + (size_t)gk * RS + sd0;
          a = *(const short8*)p;
          b2 = *(const short8*)(p + 8);
        }
        *(short8*)&Ks[skk][sd0] = a;
        *(short8*)&Ks[skk][sd0 + 8] = b2;
      } else {
        short8 a = z8;
        if (gk < Tk) a = *(const short8*)(Kb + (size_t)gk * RS + sd0);
        *(short8*)&Ks[skk][sd0] = a;
      }
    }
    // ---- stage V transposed: 4 rows x (DH/16) cols, reg transpose, b64 writes ----
    {
      short4v vrow[4];
      #pragma unroll
      for (int i2 = 0; i2 < 4; i2++) {
        const int gk = k0 + vk + i2;
        short4v t = {0, 0, 0, 0};
        if (DH == 64) {
          if (gk < Tk) t = *(const short4v*)(Vb + (size_t)gk * RS + vd0);
        } else {
          if (gk < Tk) {
            ushort2 u = *(const ushort2*)(Vb + (size_t)gk * RS + vd0);
            t[0] = (short)u.x; t[1] = (short)u.y;
          }
        }
        vrow[i2] = t;
      }
      #pragma unroll
      for (int i = 0; i < DH / 16; i++) {
        short4v w = {vrow[0][i], vrow[1][i], vrow[2][i], vrow[3][i]};
        *(short4v*)&Vt[vd0 + i][vk] = w;
      }
    }
    __syncthreads();

    // ---- scores S^T = K·Q^T, exp, pack P ----
    short8 kf[2][NC];
    #pragma unroll
    for (int kc = 0; kc < 2; kc++)
      #pragma unroll
      for (int c = 0; c < NC; c++)
        kf[kc][c] = *(const short8*)&Ks[kc * 16 + ln][c * 32 + quad * 8];

    #pragma unroll
    for (int qs = 0; qs < 2; qs++) {
      #pragma unroll
      for (int kc = 0; kc < 2; kc++) {
        f32x4 s = zf;
        #pragma unroll
        for (int c = 0; c < NC; c++)
          s = __builtin_amdgcn_mfma_f32_16x16x32_bf16(kf[kc][c], qf[qs][c], s, 0, 0, 0);
        float p[4];
        #pragma unroll
        for (int r = 0; r < 4; r++) {
          const int key = k0 + kc * 16 + quad * 4 + r;
          p[r] = (key < Tk) ? __expf(s[r]) : 0.f;
          lsum[qs] += p[r];
        }
        short4v w;
        ((u32*)&w)[0] = pack2(p[0], p[1]);
        ((u32*)&w)[1] = pack2(p[2], p[3]);
        *(short4v*)&Pb[wv][qs * 16 + ln][kc * 16 + quad * 4] = w;
      }
    }

    // ---- PV: O += P·V (per-wave Pb, no barrier needed) ----
    short8 pf2[2];
    #pragma unroll
    for (int qs = 0; qs < 2; qs++)
      pf2[qs] = *(const short8*)&Pb[wv][qs * 16 + ln][quad * 8];
    #pragma unroll
    for (int c = 0; c < NM; c++) {
      const short8 vf = *(const short8*)&Vt[c * 16 + ln][quad * 8];
      #pragma unroll
      for (int qs = 0; qs < 2; qs++)
        oacc[qs][c] = __builtin_amdgcn_mfma_f32_16x16x32_bf16(pf2[qs], vf, oacc[qs][c], 0, 0, 0);
    }
  }

  // ---- epilogue: reduce l across quads, divide, store ----
  float lq[2];
  #pragma unroll
  for (int qs = 0; qs < 2; qs++) {
    float t = lsum[qs];
    t += __shfl_xor(t, 16);
    t += __shfl_xor(t, 32);
    lq[qs] = t;
  }
  #pragma unroll
  for (int qs = 0; qs < 2; qs++) {
    #pragma unroll
    for (int r = 0; r < 4; r++) {
      const float linv = 1.f / __shfl(lq[qs], quad * 4 + r);
      const int gq = q0 + wv * 32 + qs * 16 + quad * 4 + r;
      if (gq >= Tq) continue;
      #pragma unroll
      for (int c = 0; c < NM; c++)
        Ob[(size_t)gq * RS + c * 16 + ln] = f2bf(oacc[qs][c][r] * linv);
    }
  }
}

// ---------------------------------------------------------------------------
// Grouped 3x3 conv (groups=256, 2ch/group) -> d_out (pos path), fp32
// ---------------------------------------------------------------------------
__global__ void conv_pos(const float* __restrict__ x,
                         const float* __restrict__ cw,
                         const float* __restrict__ cb,
                         float* __restrict__ out)
{
  const int idx = blockIdx.x * 256 + threadIdx.x;
  if (idx >= Bc * Tt * Cc) return;
  const int c = idx & 511;
  const int bt = idx >> 9;
  const int t = bt % Tt;
  const int b = bt / Tt;
  if (t == 0) { out[idx] = 0.f; return; }
  const int p = t - 1;
  const int hh = p >> 5, ww = p & 31;
  const float* wp = cw + c * 18;
  const int ci = (c >> 1) << 1;
  float s = cb[c];
  #pragma unroll
  for (int kh = 0; kh < 3; kh++) {
    const int h2 = hh + kh - 1;
    if ((unsigned)h2 > 31u) continue;
    #pragma unroll
    for (int kw = 0; kw < 3; kw++) {
      const int w2 = ww + kw - 1;
      if ((unsigned)w2 > 31u) continue;
      const float* xp = x + ((size_t)(b * Tt) + 1 + h2 * 32 + w2) * Cc + ci;
      s += xp[0] * wp[0 * 9 + kh * 3 + kw] + xp[1] * wp[1 * 9 + kh * 3 + kw];
    }
  }
  out[idx] = s;
}

// cat = [gr (bcast) | x_summary] bf16
__global__ void build_cat(const float* __restrict__ gr_cache,
                          const float* __restrict__ x_self,
                          u16* __restrict__ cat)
{
  const int idx = blockIdx.x * 256 + threadIdx.x;
  if (idx >= Bc * Ll * 512) return;
  const int k = idx & 511;
  const int bi = idx >> 9;
  const int i = bi & 255;
  const int b = bi >> 8;
  float v;
  if (k < 256) v = gr_cache[i * 256 + k];
  else         v = x_self[((size_t)(b * Tt + 4 * i)) * Cc + (k - 256)];
  cat[idx] = f2bf(v);
}

// cat[:, :256] = bf16(reset * gr)
__global__ void build_cat2(const float* __restrict__ gr_cache,
                           const float* __restrict__ reset,
                           u16* __restrict__ cat)
{
  const int idx = blockIdx.x * 256 + threadIdx.x;
  if (idx >= Bc * Ll * 256) return;
  const int k = idx & 255;
  const int bi = idx >> 8;
  const int i = bi & 255;
  cat[(size_t)bi * 512 + k] = f2bf(gr_cache[i * 256 + k] * reset[idx]);
}

// LayerNorm + gate -> gr_new bf16
__device__ inline float block_sum256(float v, float* red)
{
  #pragma unroll
  for (int o = 32; o >= 1; o >>= 1) v += __shfl_down(v, o);
  const int wid = threadIdx.x >> 6;
  if ((threadIdx.x & 63) == 0) red[wid] = v;
  __syncthreads();
  const float t = red[0] + red[1] + red[2] + red[3];
  __syncthreads();
  return t;
}

__global__ __launch_bounds__(256) void ln_gate(
    const float* __restrict__ add_raw, const float* __restrict__ z,
    const float* __restrict__ gr_cache, const float* __restrict__ gamma,
    const float* __restrict__ beta, u16* __restrict__ gr_new)
{
  __shared__ float red[4];
  const int bi = blockIdx.x;
  const int i = bi & 255;
  const int c = threadIdx.x;
  const float v = add_raw[(size_t)bi * 256 + c];
  const float mu = block_sum256(v, red) * (1.f / 256.f);
  const float dv = v - mu;
  const float var = block_sum256(dv * dv, red) * (1.f / 256.f);
  const float nrm = dv * rsqrtf(var + 1e-5f) * gamma[c] + beta[c];
  const float zz = z[(size_t)bi * 256 + c];
  gr_new[(size_t)bi * 256 + c] = f2bf(zz * nrm + (1.f - zz) * gr_cache[i * 256 + c]);
}

// out += alpha_h * pad(x_mem) + (1-alpha_h) * x_self
__global__ void combine(const float* __restrict__ x_self,
                        const float* __restrict__ x_mem,
                        const float* __restrict__ lam,
                        float* __restrict__ out)
{
  const int idx = blockIdx.x * 256 + threadIdx.x;
  if (idx >= Bc * Tt * Cc) return;
  const int c = idx & 511;
  const int bt = idx >> 9;
  const int hh = c >> 6;
  const int dd = c & 63;
  const float alpha = 1.f / (1.f + __expf(-lam[hh]));
  const float mem = (dd < 32) ? x_mem[(size_t)bt * 256 + hh * 32 + dd] : 0.f;
  out[idx] += alpha * mem + (1.f - alpha) * x_self[idx];
}

// ---------------------------------------------------------------------------
extern "C" void kernel_launch(void* const* d_in, const int* in_sizes, int n_in,
                              void* d_out, int out_size, void* d_ws, size_t ws_size,
                              hipStream_t stream)
{
  const float* x        = (const float*)d_in[0];
  const float* gr_cache = (const float*)d_in[1];
  const float* Wq1 = (const float*)d_in[2];  const float* bq1 = (const float*)d_in[3];
  const float* Wk1 = (const float*)d_in[4];  const float* bk1 = (const float*)d_in[5];
  const float* Wv1 = (const float*)d_in[6];  const float* bv1 = (const float*)d_in[7];
  const float* Wo1 = (const float*)d_in[8];  const float* bo1 = (const float*)d_in[9];
  const float* Wq2 = (const float*)d_in[10]; const float* bq2 = (const float*)d_in[11];
  const float* Wk2 = (const float*)d_in[12]; const float* bk2 = (const float*)d_in[13];
  const float* Wv2 = (const float*)d_in[14]; const float* bv2 = (const float*)d_in[15];
  const float* Wo2 = (const float*)d_in[16]; const float* bo2 = (const float*)d_in[17];
  const float* Wr  = (const float*)d_in[18]; const float* br  = (const float*)d_in[19];
  const float* Wz  = (const float*)d_in[20]; const float* bz  = (const float*)d_in[21];
  const float* Wa  = (const float*)d_in[22]; const float* ba  = (const float*)d_in[23];
  const float* gamma = (const float*)d_in[24];
  const float* beta  = (const float*)d_in[25];
  const float* lam   = (const float*)d_in[26];
  const float* conv_w = (const float*)d_in[27];
  const float* conv_b = (const float*)d_in[28];
  float* out = (float*)d_out;

  const int M1 = Bc * Tt;       // 8200
  const int M2 = Bc * Ll;       // 2048
  const size_t BTC = (size_t)Bc * Tt * Cc;    // 4,198,400
  const size_t BLA = (size_t)Bc * Ll * CA;
  const size_t BL2 = (size_t)Bc * Ll * 512;

  char* W = (char*)d_ws;
  // phase-1 layout (bytes)
  u16*   xb     = (u16*)(W + 0);                       // 8,396,800 B
  u16*   q1     = (u16*)(W + 8396800);
  u16*   k1     = (u16*)(W + 16793600);
  u16*   v1     = (u16*)(W + 25190400);
  u16*   att1   = (u16*)(W + 33587200);
  float* x_self = (float*)(W + 41984000);              // 16,793,600 B
  u16*   wtb    = (u16*)(W + 58777600);                // 3,407,872 B
  // phase-2 overlay (q1/k1/v1 region dead by then)
  u16*   cat    = (u16*)(W + 8396800);
  float* rg     = (float*)(W + 10493952);
  float* zg     = (float*)(W + 12591104);
  float* addr_  = (float*)(W + 14688256);
  u16*   gr_new = (u16*)(W + 16785408);
  u16*   k2     = (u16*)(W + 17833984);
  u16*   v2     = (u16*)(W + 18882560);
  u16*   q2     = (u16*)(W + 19931136);
  u16*   att2   = (u16*)(W + 24129536);
  float* x_mem  = (float*)(W + 28327936);

  u16* Wq1t = wtb + 0;       u16* Wk1t = wtb + 262144;  u16* Wv1t = wtb + 524288;
  u16* Wo1t = wtb + 786432;  u16* Wrt  = wtb + 1048576; u16* Wzt  = wtb + 1179648;
  u16* Wat  = wtb + 1310720; u16* Wq2t = wtb + 1441792; u16* Wk2t = wtb + 1507328;
  u16* Wv2t = wtb + 1572864; u16* Wo2t = wtb + 1638400;

  const dim3 blk(256);
  const int ew_btc = (int)((BTC + 255) / 256);

  // ---- casts ----
  {
    WCP p;
    const float* ws_[11] = {Wq1, Wk1, Wv1, Wo1, Wr, Wz, Wa, Wq2, Wk2, Wv2, Wo2};
    u16* wd_[11] = {Wq1t, Wk1t, Wv1t, Wo1t, Wrt, Wzt, Wat, Wq2t, Wk2t, Wv2t, Wo2t};
    const int Kk[11] = {512,512,512,512,512,512,512,256,256,256,256};
    const int Nn[11] = {512,512,512,512,256,256,256,256,256,256,256};
    for (int i = 0; i < 11; i++) {
      p.w[i].s = ws_[i]; p.w[i].d = wd_[i]; p.w[i].N = Nn[i];
      p.w[i].tot = Kk[i] * Nn[i];
      p.w[i].kshift = (Kk[i] == 512) ? 9 : 8;
    }
    wcast_k<<<dim3(64, 11), blk, 0, stream>>>(p);
  }
  xcast_k<<<ew_btc, blk, 0, stream>>>(x, xb, (int)BTC);

  // pos path -> d_out
  conv_pos<<<ew_btc, blk, 0, stream>>>(x, conv_w, conv_b, out);

  // ---- MHA1 ----  (softmax scale folded into Q projection)
  const dim3 g512(4, 65), g256m1(2, 65), g256m2(2, 16);
  gemm_mfma<1, EP_NONE><<<g512, blk, 0, stream>>>(xb, 512, Wq1t, bq1, q1, M1, 512, 512, 0.125f);
  gemm_mfma<1, EP_NONE><<<g512, blk, 0, stream>>>(xb, 512, Wk1t, bk1, k1, M1, 512, 512, 1.f);
  gemm_mfma<1, EP_NONE><<<g512, blk, 0, stream>>>(xb, 512, Wv1t, bv1, v1, M1, 512, 512, 1.f);
  attn_mfma<64><<<dim3(17, 64), dim3(128), 0, stream>>>(q1, k1, v1, att1, Tt, Tt,
                                                        Tt * 512, Tt * 512);
  gemm_mfma<0, EP_NONE><<<g512, blk, 0, stream>>>(att1, 512, Wo1t, bo1, x_self, M1, 512, 512, 1.f);

  // ---- GRU cache update ----
  build_cat<<<(int)((BL2 + 255) / 256), blk, 0, stream>>>(gr_cache, x_self, cat);
  gemm_mfma<0, EP_SIGMOID><<<g256m2, blk, 0, stream>>>(cat, 512, Wrt, br, rg, M2, 256, 512, 1.f);
  gemm_mfma<0, EP_SIGMOID><<<g256m2, blk, 0, stream>>>(cat, 512, Wzt, bz, zg, M2, 256, 512, 1.f);
  build_cat2<<<(int)((BLA + 255) / 256), blk, 0, stream>>>(gr_cache, rg, cat);
  gemm_mfma<0, EP_GELU><<<g256m2, blk, 0, stream>>>(cat, 512, Wat, ba, addr_, M2, 256, 512, 1.f);
  ln_gate<<<M2, blk, 0, stream>>>(addr_, zg, gr_cache, gamma, beta, gr_new);

  // ---- MHA2 ----
  gemm_mfma<1, EP_NONE><<<g256m1, blk, 0, stream>>>(xb, 512, Wq2t, bq2, q2, M1, 256, 256,
                                                    0.17677669529663689f);
  gemm_mfma<1, EP_NONE><<<g256m2, blk, 0, stream>>>(gr_new, 256, Wk2t, bk2, k2, M2, 256, 256, 1.f);
  gemm_mfma<1, EP_NONE><<<g256m2, blk, 0, stream>>>(gr_new, 256, Wv2t, bv2, v2, M2, 256, 256, 1.f);
  attn_mfma<32><<<dim3(17, 64), dim3(128), 0, stream>>>(q2, k2, v2, att2, Tt, Ll,
                                                        Tt * 256, Ll * 256);
  gemm_mfma<0, EP_NONE><<<g256m1, blk, 0, stream>>>(att2, 256, Wo2t, bo2, x_mem, M1, 256, 256, 1.f);

  // final mix
  combine<<<ew_btc, blk, 0, stream>>>(x_self, x_mem, lam, out);
}

// Round 5
// 407.099 us; speedup vs baseline: 3.6703x; 1.1686x over previous
//
#include <hip/hip_runtime.h>
#include <math.h>

typedef unsigned short u16;
typedef unsigned int u32;
typedef __attribute__((ext_vector_type(8))) short short8;
typedef __attribute__((ext_vector_type(4))) short short4v;
typedef __attribute__((ext_vector_type(4))) float f32x4;

// Problem constants
constexpr int Bc = 8;
constexpr int Tt = 1025;
constexpr int Cc = 512;
constexpr int Hn = 8;
constexpr int CA = 256;
constexpr int Ll = 256;

__device__ __forceinline__ u16 f2bf(float f) {
  u32 u = __builtin_bit_cast(u32, f);
  u = (u + 0x7FFFu + ((u >> 16) & 1u)) >> 16;
  return (u16)u;
}
// pack two fp32 -> bf16x2 word (RNE)
__device__ __forceinline__ u32 pack2(float lo, float hi) {
  return (u32)f2bf(lo) | ((u32)f2bf(hi) << 16);
}

// ---------------------------------------------------------------------------
// Weight cast+transpose: W[K][N] fp32 -> Wt[N][K] bf16.
// ---------------------------------------------------------------------------
struct WC { const float* s; u16* d; int N; int tot; int kshift; };
struct WCP { WC w[11]; };

__global__ void wcast_k(WCP p) {
  const WC a = p.w[blockIdx.y];
  const int kmask = (1 << a.kshift) - 1;
  for (int idx = blockIdx.x * 256 + threadIdx.x; idx < a.tot; idx += gridDim.x * 256) {
    const int k = idx & kmask;
    const int n = idx >> a.kshift;
    a.d[idx] = f2bf(a.s[(size_t)k * a.N + n]);
  }
}

__global__ void xcast_k(const float* __restrict__ x, u16* __restrict__ xb, int n) {
  const int i = blockIdx.x * 256 + threadIdx.x;
  if (i < n) xb[i] = f2bf(x[i]);
}

// ---------------------------------------------------------------------------
// bf16 MFMA GEMM: C[M,N] = ((A[M,K] @ W) + bias) * oscale, epilogue act.
// 128x128 tile, BK=32, 256 thr = 4 waves, each 64x64 (4x4 of 16x16x32).
// ---------------------------------------------------------------------------
enum { EP_NONE = 0, EP_SIGMOID = 1, EP_GELU = 2 };

template <int OUTBF, int ACT>
__global__ __launch_bounds__(256) void gemm_mfma(
    const u16* __restrict__ A, int lda,
    const u16* __restrict__ Wt,
    const float* __restrict__ bias,
    void* __restrict__ Cout,
    int M, int N, int K, float oscale)
{
  __shared__ u16 As[128][32];
  __shared__ u16 Bs[128][32];
  const int tid = threadIdx.x;
  const int m0 = blockIdx.y * 128, n0 = blockIdx.x * 128;
  const int ln = tid & 15, quad = (tid >> 4) & 3, wv = tid >> 6;
  const int wm = (wv & 1) * 64, wn = (wv >> 1) * 64;
  const int sr = tid >> 1;
  const int sk = (tid & 1) * 16;

  f32x4 zf = {0.f, 0.f, 0.f, 0.f};
  f32x4 acc[4][4];
  #pragma unroll
  for (int i = 0; i < 4; i++)
    #pragma unroll
    for (int j = 0; j < 4; j++) acc[i][j] = zf;

  const short8 z8 = {0, 0, 0, 0, 0, 0, 0, 0};

  for (int k0 = 0; k0 < K; k0 += 32) {
    const int gm = m0 + sr;
    short8 a0 = z8, a1 = z8;
    if (gm < M) {
      const u16* p = A + (size_t)gm * lda + k0 + sk;
      a0 = *(const short8*)p;
      a1 = *(const short8*)(p + 8);
    }
    *(short8*)&As[sr][sk] = a0;
    *(short8*)&As[sr][sk + 8] = a1;
    {
      const u16* q = Wt + (size_t)(n0 + sr) * K + k0 + sk;
      *(short8*)&Bs[sr][sk] = *(const short8*)q;
      *(short8*)&Bs[sr][sk + 8] = *(const short8*)(q + 8);
    }
    __syncthreads();

    short8 af[4], bf[4];
    #pragma unroll
    for (int i = 0; i < 4; i++) af[i] = *(const short8*)&As[wm + i * 16 + ln][quad * 8];
    #pragma unroll
    for (int j = 0; j < 4; j++) bf[j] = *(const short8*)&Bs[wn + j * 16 + ln][quad * 8];
    #pragma unroll
    for (int i = 0; i < 4; i++)
      #pragma unroll
      for (int j = 0; j < 4; j++)
        acc[i][j] = __builtin_amdgcn_mfma_f32_16x16x32_bf16(af[i], bf[j], acc[i][j], 0, 0, 0);
    __syncthreads();
  }

  float bj[4];
  #pragma unroll
  for (int j = 0; j < 4; j++) bj[j] = bias[n0 + wn + j * 16 + ln];

  #pragma unroll
  for (int i = 0; i < 4; i++) {
    #pragma unroll
    for (int r = 0; r < 4; r++) {
      const int gm = m0 + wm + i * 16 + quad * 4 + r;
      if (gm >= M) continue;
      #pragma unroll
      for (int j = 0; j < 4; j++) {
        float v = (acc[i][j][r] + bj[j]) * oscale;
        if (ACT == EP_SIGMOID)   v = 1.f / (1.f + __expf(-v));
        else if (ACT == EP_GELU) v = 0.5f * v * (1.f + erff(v * 0.70710678118654752f));
        const size_t off = (size_t)gm * N + n0 + wn + j * 16 + ln;
        if (OUTBF) ((u16*)Cout)[off] = f2bf(v);
        else       ((float*)Cout)[off] = v;
      }
    }
  }
}

// ---------------------------------------------------------------------------
// MFMA flash attention v3 (transposed scores, no-max softmax).
// ---------------------------------------------------------------------------
template <int DH>
__global__ __launch_bounds__(128) void attn_mfma(
    const u16* __restrict__ Qp, const u16* __restrict__ Kp,
    const u16* __restrict__ Vp, u16* __restrict__ Op,
    int Tq, int Tk, int qbs, int kbs)
{
  constexpr int RS = Hn * DH;     // row stride (elements)
  constexpr int KS = DH + 8;      // Ks stride
  constexpr int VS = 40;          // Vt / Pb key-stride
  constexpr int NC = DH / 32;     // d-chunks for scores
  constexpr int NM = DH / 16;     // d-tiles for output

  __shared__ u16 Ks[32][KS];      // K tile [key][d]
  __shared__ u16 Vt[DH][VS];      // V^T tile [d][key]
  __shared__ u16 Pb[2][32][VS];   // per-wave P [q][key]

  const int b = blockIdx.y >> 3, h = blockIdx.y & 7;
  const int q0 = blockIdx.x * 64;
  const int tid = threadIdx.x;
  const int wv = tid >> 6;
  const int lane = tid & 63;
  const int ln = lane & 15, quad = lane >> 4;

  const u16* Qb = Qp + (size_t)b * qbs + h * DH;
  const u16* Kb = Kp + (size_t)b * kbs + h * DH;
  const u16* Vb = Vp + (size_t)b * kbs + h * DH;
  u16* Ob = Op + (size_t)b * qbs + h * DH;

  const short8 z8 = {0, 0, 0, 0, 0, 0, 0, 0};
  const f32x4 zf = {0.f, 0.f, 0.f, 0.f};

  // Q fragments: content Q[q=ln][d=c*32+quad*8+j] (B-operand = Q^T)
  short8 qf[2][NC];
  #pragma unroll
  for (int qs = 0; qs < 2; qs++) {
    const int gq = q0 + wv * 32 + qs * 16 + ln;
    #pragma unroll
    for (int c = 0; c < NC; c++) {
      if (gq < Tq) qf[qs][c] = *(const short8*)(Qb + (size_t)gq * RS + c * 32 + quad * 8);
      else         qf[qs][c] = z8;
    }
  }

  f32x4 oacc[2][NM];
  float lsum[2] = {0.f, 0.f};
  #pragma unroll
  for (int qs = 0; qs < 2; qs++)
    #pragma unroll
    for (int c = 0; c < NM; c++) oacc[qs][c] = zf;

  // staging maps
  const int skk = tid >> 2;                 // K row 0..31
  const int sd0 = (tid & 3) * (DH / 4);     // K col chunk
  const int vd0 = (tid & 15) * (DH / 16);   // V d chunk (4 or 2 cols)
  const int vk  = (tid >> 4) * 4;           // V key group (4 rows)

  const int nit = (Tk + 31) >> 5;
  for (int it = 0; it < nit; it++) {
    const int k0 = it << 5;
    __syncthreads();
    // ---- stage K [key][d] ----
    {
      const int gk = k0 + skk;
      if (DH == 64) {
        short8 a = z8, b2 = z8;
        if (gk < Tk) {
          const u16* p = Kb + (size_t)gk * RS + sd0;
          a = *(const short8*)p;
          b2 = *(const short8*)(p + 8);
        }
        *(short8*)&Ks[skk][sd0] = a;
        *(short8*)&Ks[skk][sd0 + 8] = b2;
      } else {
        short8 a = z8;
        if (gk < Tk) a = *(const short8*)(Kb + (size_t)gk * RS + sd0);
        *(short8*)&Ks[skk][sd0] = a;
      }
    }
    // ---- stage V transposed: 4 rows x (DH/16) cols, reg transpose, b64 writes ----
    {
      short4v vrow[4];
      #pragma unroll
      for (int i2 = 0; i2 < 4; i2++) {
        const int gk = k0 + vk + i2;
        short4v t = {0, 0, 0, 0};
        if (DH == 64) {
          if (gk < Tk) t = *(const short4v*)(Vb + (size_t)gk * RS + vd0);
        } else {
          if (gk < Tk) {
            ushort2 u = *(const ushort2*)(Vb + (size_t)gk * RS + vd0);
            t[0] = (short)u.x; t[1] = (short)u.y;
          }
        }
        vrow[i2] = t;
      }
      #pragma unroll
      for (int i = 0; i < DH / 16; i++) {
        short4v w = {vrow[0][i], vrow[1][i], vrow[2][i], vrow[3][i]};
        *(short4v*)&Vt[vd0 + i][vk] = w;
      }
    }
    __syncthreads();

    // ---- scores S^T = K·Q^T, exp, pack P ----
    short8 kf[2][NC];
    #pragma unroll
    for (int kc = 0; kc < 2; kc++)
      #pragma unroll
      for (int c = 0; c < NC; c++)
        kf[kc][c] = *(const short8*)&Ks[kc * 16 + ln][c * 32 + quad * 8];

    #pragma unroll
    for (int qs = 0; qs < 2; qs++) {
      #pragma unroll
      for (int kc = 0; kc < 2; kc++) {
        f32x4 s = zf;
        #pragma unroll
        for (int c = 0; c < NC; c++)
          s = __builtin_amdgcn_mfma_f32_16x16x32_bf16(kf[kc][c], qf[qs][c], s, 0, 0, 0);
        float p[4];
        #pragma unroll
        for (int r = 0; r < 4; r++) {
          const int key = k0 + kc * 16 + quad * 4 + r;
          p[r] = (key < Tk) ? __expf(s[r]) : 0.f;
          lsum[qs] += p[r];
        }
        short4v w;
        ((u32*)&w)[0] = pack2(p[0], p[1]);
        ((u32*)&w)[1] = pack2(p[2], p[3]);
        *(short4v*)&Pb[wv][qs * 16 + ln][kc * 16 + quad * 4] = w;
      }
    }

    // ---- PV: O += P·V (per-wave Pb, no barrier needed) ----
    short8 pf2[2];
    #pragma unroll
    for (int qs = 0; qs < 2; qs++)
      pf2[qs] = *(const short8*)&Pb[wv][qs * 16 + ln][quad * 8];
    #pragma unroll
    for (int c = 0; c < NM; c++) {
      const short8 vf = *(const short8*)&Vt[c * 16 + ln][quad * 8];
      #pragma unroll
      for (int qs = 0; qs < 2; qs++)
        oacc[qs][c] = __builtin_amdgcn_mfma_f32_16x16x32_bf16(pf2[qs], vf, oacc[qs][c], 0, 0, 0);
    }
  }

  // ---- epilogue: reduce l across quads, divide, store ----
  float lq[2];
  #pragma unroll
  for (int qs = 0; qs < 2; qs++) {
    float t = lsum[qs];
    t += __shfl_xor(t, 16);
    t += __shfl_xor(t, 32);
    lq[qs] = t;
  }
  #pragma unroll
  for (int qs = 0; qs < 2; qs++) {
    #pragma unroll
    for (int r = 0; r < 4; r++) {
      const float linv = 1.f / __shfl(lq[qs], quad * 4 + r);
      const int gq = q0 + wv * 32 + qs * 16 + quad * 4 + r;
      if (gq >= Tq) continue;
      #pragma unroll
      for (int c = 0; c < NM; c++)
        Ob[(size_t)gq * RS + c * 16 + ln] = f2bf(oacc[qs][c][r] * linv);
    }
  }
}

// ---------------------------------------------------------------------------
// FUSED grouped-conv (pos) + final combine:
//   out[b,t,c] = pos(b,t,c) + alpha_h*pad(x_mem) + (1-alpha_h)*x_self
// Grid: (Bc*32 rows, 2 channel halves), 256 thr; thread = one channel c,
// slides a 3x3x2 register window along w (3 new 8B loads per output).
// Conv weights live in registers (loaded once per thread) -> no 72B-stride
// gather per tap (the R4 conv_pos killer).
// ---------------------------------------------------------------------------
__global__ __launch_bounds__(256) void conv_combine(
    const float* __restrict__ x, const float* __restrict__ cw,
    const float* __restrict__ cb, const float* __restrict__ x_self,
    const float* __restrict__ x_mem, const float* __restrict__ lam,
    float* __restrict__ out)
{
  const int bh = blockIdx.x;               // b*32 + h
  const int b = bh >> 5, hh = bh & 31;
  const int c = (blockIdx.y << 8) + threadIdx.x;   // 0..511
  const int ci = c & ~1;
  const int dd = c & 63;
  const int h8 = c >> 6;
  const float alpha = 1.f / (1.f + __expf(-lam[h8]));
  const float bias = cb[c];

  // conv weights -> registers (one-time)
  float wgt[2][9];
  #pragma unroll
  for (int ch = 0; ch < 2; ch++)
    #pragma unroll
    for (int k = 0; k < 9; k++) wgt[ch][k] = cw[c * 18 + ch * 9 + k];

  // row pointers + validity
  const float* xrow[3];
  bool rv[3];
  #pragma unroll
  for (int r = 0; r < 3; r++) {
    const int h2 = hh + r - 1;
    rv[r] = (unsigned)h2 < 32u;
    xrow[r] = x + ((size_t)(b * Tt) + 1 + h2 * 32) * Cc + ci;
  }

  // sliding window win[r][col]: col 0 = w-1, 1 = w, 2 = w+1
  float2 win[3][3];
  #pragma unroll
  for (int r = 0; r < 3; r++) {
    win[r][0] = make_float2(0.f, 0.f);     // col -1 (pad)
    win[r][1] = rv[r] ? *(const float2*)(xrow[r]) : make_float2(0.f, 0.f);
  }

  const size_t bT = (size_t)b * Tt;
  for (int w = 0; w < 32; w++) {
    #pragma unroll
    for (int r = 0; r < 3; r++)
      win[r][2] = (rv[r] && w + 1 < 32) ? *(const float2*)(xrow[r] + (w + 1) * Cc)
                                        : make_float2(0.f, 0.f);
    float pos = bias;
    #pragma unroll
    for (int r = 0; r < 3; r++)
      #pragma unroll
      for (int col = 0; col < 3; col++) {
        pos += win[r][col].x * wgt[0][r * 3 + col];
        pos += win[r][col].y * wgt[1][r * 3 + col];
      }
    const size_t bt = bT + 1 + hh * 32 + w;
    const float mem = (dd < 32) ? x_mem[bt * 256 + h8 * 32 + dd] : 0.f;
    out[bt * 512 + c] = pos + alpha * mem + (1.f - alpha) * x_self[bt * 512 + c];
    #pragma unroll
    for (int r = 0; r < 3; r++) { win[r][0] = win[r][1]; win[r][1] = win[r][2]; }
  }

  // CLS row (t==0, pos=0) handled by the hh==0 blocks
  if (hh == 0) {
    const float mem = (dd < 32) ? x_mem[bT * 256 + h8 * 32 + dd] : 0.f;
    out[bT * 512 + c] = alpha * mem + (1.f - alpha) * x_self[bT * 512 + c];
  }
}

// cat = [gr (bcast) | x_summary] bf16
__global__ void build_cat(const float* __restrict__ gr_cache,
                          const float* __restrict__ x_self,
                          u16* __restrict__ cat)
{
  const int idx = blockIdx.x * 256 + threadIdx.x;
  if (idx >= Bc * Ll * 512) return;
  const int k = idx & 511;
  const int bi = idx >> 9;
  const int i = bi & 255;
  const int b = bi >> 8;
  float v;
  if (k < 256) v = gr_cache[i * 256 + k];
  else         v = x_self[((size_t)(b * Tt + 4 * i)) * Cc + (k - 256)];
  cat[idx] = f2bf(v);
}

// cat[:, :256] = bf16(reset * gr)
__global__ void build_cat2(const float* __restrict__ gr_cache,
                           const float* __restrict__ reset,
                           u16* __restrict__ cat)
{
  const int idx = blockIdx.x * 256 + threadIdx.x;
  if (idx >= Bc * Ll * 256) return;
  const int k = idx & 255;
  const int bi = idx >> 8;
  const int i = bi & 255;
  cat[(size_t)bi * 512 + k] = f2bf(gr_cache[i * 256 + k] * reset[idx]);
}

// LayerNorm + gate -> gr_new bf16
__device__ inline float block_sum256(float v, float* red)
{
  #pragma unroll
  for (int o = 32; o >= 1; o >>= 1) v += __shfl_down(v, o);
  const int wid = threadIdx.x >> 6;
  if ((threadIdx.x & 63) == 0) red[wid] = v;
  __syncthreads();
  const float t = red[0] + red[1] + red[2] + red[3];
  __syncthreads();
  return t;
}

__global__ __launch_bounds__(256) void ln_gate(
    const float* __restrict__ add_raw, const float* __restrict__ z,
    const float* __restrict__ gr_cache, const float* __restrict__ gamma,
    const float* __restrict__ beta, u16* __restrict__ gr_new)
{
  __shared__ float red[4];
  const int bi = blockIdx.x;
  const int i = bi & 255;
  const int c = threadIdx.x;
  const float v = add_raw[(size_t)bi * 256 + c];
  const float mu = block_sum256(v, red) * (1.f / 256.f);
  const float dv = v - mu;
  const float var = block_sum256(dv * dv, red) * (1.f / 256.f);
  const float nrm = dv * rsqrtf(var + 1e-5f) * gamma[c] + beta[c];
  const float zz = z[(size_t)bi * 256 + c];
  gr_new[(size_t)bi * 256 + c] = f2bf(zz * nrm + (1.f - zz) * gr_cache[i * 256 + c]);
}

// ---------------------------------------------------------------------------
extern "C" void kernel_launch(void* const* d_in, const int* in_sizes, int n_in,
                              void* d_out, int out_size, void* d_ws, size_t ws_size,
                              hipStream_t stream)
{
  const float* x        = (const float*)d_in[0];
  const float* gr_cache = (const float*)d_in[1];
  const float* Wq1 = (const float*)d_in[2];  const float* bq1 = (const float*)d_in[3];
  const float* Wk1 = (const float*)d_in[4];  const float* bk1 = (const float*)d_in[5];
  const float* Wv1 = (const float*)d_in[6];  const float* bv1 = (const float*)d_in[7];
  const float* Wo1 = (const float*)d_in[8];  const float* bo1 = (const float*)d_in[9];
  const float* Wq2 = (const float*)d_in[10]; const float* bq2 = (const float*)d_in[11];
  const float* Wk2 = (const float*)d_in[12]; const float* bk2 = (const float*)d_in[13];
  const float* Wv2 = (const float*)d_in[14]; const float* bv2 = (const float*)d_in[15];
  const float* Wo2 = (const float*)d_in[16]; const float* bo2 = (const float*)d_in[17];
  const float* Wr  = (const float*)d_in[18]; const float* br  = (const float*)d_in[19];
  const float* Wz  = (const float*)d_in[20]; const float* bz  = (const float*)d_in[21];
  const float* Wa  = (const float*)d_in[22]; const float* ba  = (const float*)d_in[23];
  const float* gamma = (const float*)d_in[24];
  const float* beta  = (const float*)d_in[25];
  const float* lam   = (const float*)d_in[26];
  const float* conv_w = (const float*)d_in[27];
  const float* conv_b = (const float*)d_in[28];
  float* out = (float*)d_out;

  const int M1 = Bc * Tt;       // 8200
  const int M2 = Bc * Ll;       // 2048
  const size_t BTC = (size_t)Bc * Tt * Cc;    // 4,198,400
  const size_t BLA = (size_t)Bc * Ll * CA;
  const size_t BL2 = (size_t)Bc * Ll * 512;

  char* W = (char*)d_ws;
  // phase-1 layout (bytes)
  u16*   xb     = (u16*)(W + 0);                       // 8,396,800 B
  u16*   q1     = (u16*)(W + 8396800);
  u16*   k1     = (u16*)(W + 16793600);
  u16*   v1     = (u16*)(W + 25190400);
  u16*   att1   = (u16*)(W + 33587200);
  float* x_self = (float*)(W + 41984000);              // 16,793,600 B
  u16*   wtb    = (u16*)(W + 58777600);                // 3,407,872 B
  // phase-2 overlay (q1/k1/v1 region dead by then)
  u16*   cat    = (u16*)(W + 8396800);
  float* rg     = (float*)(W + 10493952);
  float* zg     = (float*)(W + 12591104);
  float* addr_  = (float*)(W + 14688256);
  u16*   gr_new = (u16*)(W + 16785408);
  u16*   k2     = (u16*)(W + 17833984);
  u16*   v2     = (u16*)(W + 18882560);
  u16*   q2     = (u16*)(W + 19931136);
  u16*   att2   = (u16*)(W + 24129536);
  float* x_mem  = (float*)(W + 28327936);

  u16* Wq1t = wtb + 0;       u16* Wk1t = wtb + 262144;  u16* Wv1t = wtb + 524288;
  u16* Wo1t = wtb + 786432;  u16* Wrt  = wtb + 1048576; u16* Wzt  = wtb + 1179648;
  u16* Wat  = wtb + 1310720; u16* Wq2t = wtb + 1441792; u16* Wk2t = wtb + 1507328;
  u16* Wv2t = wtb + 1572864; u16* Wo2t = wtb + 1638400;

  const dim3 blk(256);
  const int ew_btc = (int)((BTC + 255) / 256);

  // ---- casts ----
  {
    WCP p;
    const float* ws_[11] = {Wq1, Wk1, Wv1, Wo1, Wr, Wz, Wa, Wq2, Wk2, Wv2, Wo2};
    u16* wd_[11] = {Wq1t, Wk1t, Wv1t, Wo1t, Wrt, Wzt, Wat, Wq2t, Wk2t, Wv2t, Wo2t};
    const int Kk[11] = {512,512,512,512,512,512,512,256,256,256,256};
    const int Nn[11] = {512,512,512,512,256,256,256,256,256,256,256};
    for (int i = 0; i < 11; i++) {
      p.w[i].s = ws_[i]; p.w[i].d = wd_[i]; p.w[i].N = Nn[i];
      p.w[i].tot = Kk[i] * Nn[i];
      p.w[i].kshift = (Kk[i] == 512) ? 9 : 8;
    }
    wcast_k<<<dim3(64, 11), blk, 0, stream>>>(p);
  }
  xcast_k<<<ew_btc, blk, 0, stream>>>(x, xb, (int)BTC);

  // ---- MHA1 ----  (softmax scale folded into Q projection)
  const dim3 g512(4, 65), g256m1(2, 65), g256m2(2, 16);
  gemm_mfma<1, EP_NONE><<<g512, blk, 0, stream>>>(xb, 512, Wq1t, bq1, q1, M1, 512, 512, 0.125f);
  gemm_mfma<1, EP_NONE><<<g512, blk, 0, stream>>>(xb, 512, Wk1t, bk1, k1, M1, 512, 512, 1.f);
  gemm_mfma<1, EP_NONE><<<g512, blk, 0, stream>>>(xb, 512, Wv1t, bv1, v1, M1, 512, 512, 1.f);
  attn_mfma<64><<<dim3(17, 64), dim3(128), 0, stream>>>(q1, k1, v1, att1, Tt, Tt,
                                                        Tt * 512, Tt * 512);
  gemm_mfma<0, EP_NONE><<<g512, blk, 0, stream>>>(att1, 512, Wo1t, bo1, x_self, M1, 512, 512, 1.f);

  // ---- GRU cache update ----
  build_cat<<<(int)((BL2 + 255) / 256), blk, 0, stream>>>(gr_cache, x_self, cat);
  gemm_mfma<0, EP_SIGMOID><<<g256m2, blk, 0, stream>>>(cat, 512, Wrt, br, rg, M2, 256, 512, 1.f);
  gemm_mfma<0, EP_SIGMOID><<<g256m2, blk, 0, stream>>>(cat, 512, Wzt, bz, zg, M2, 256, 512, 1.f);
  build_cat2<<<(int)((BLA + 255) / 256), blk, 0, stream>>>(gr_cache, rg, cat);
  gemm_mfma<0, EP_GELU><<<g256m2, blk, 0, stream>>>(cat, 512, Wat, ba, addr_, M2, 256, 512, 1.f);
  ln_gate<<<M2, blk, 0, stream>>>(addr_, zg, gr_cache, gamma, beta, gr_new);

  // ---- MHA2 ----
  gemm_mfma<1, EP_NONE><<<g256m1, blk, 0, stream>>>(xb, 512, Wq2t, bq2, q2, M1, 256, 256,
                                                    0.17677669529663689f);
  gemm_mfma<1, EP_NONE><<<g256m2, blk, 0, stream>>>(gr_new, 256, Wk2t, bk2, k2, M2, 256, 256, 1.f);
  gemm_mfma<1, EP_NONE><<<g256m2, blk, 0, stream>>>(gr_new, 256, Wv2t, bv2, v2, M2, 256, 256, 1.f);
  attn_mfma<32><<<dim3(17, 64), dim3(128), 0, stream>>>(q2, k2, v2, att2, Tt, Ll,
                                                        Tt * 256, Ll * 256);
  gemm_mfma<0, EP_NONE><<<g256m1, blk, 0, stream>>>(att2, 256, Wo2t, bo2, x_mem, M1, 256, 256, 1.f);

  // ---- fused conv(pos) + final mix -> d_out ----
  conv_combine<<<dim3(Bc * 32, 2), blk, 0, stream>>>(x, conv_w, conv_b, x_self,
                                                     x_mem, lam, out);
}

// Round 6
// 397.245 us; speedup vs baseline: 3.7614x; 1.0248x over previous
//
#include <hip/hip_runtime.h>
#include <math.h>

typedef unsigned short u16;
typedef unsigned int u32;
typedef __attribute__((ext_vector_type(8))) short short8;
typedef __attribute__((ext_vector_type(4))) short short4v;
typedef __attribute__((ext_vector_type(4))) float f32x4;

// Problem constants
constexpr int Bc = 8;
constexpr int Tt = 1025;
constexpr int Cc = 512;
constexpr int Hn = 8;
constexpr int CA = 256;
constexpr int Ll = 256;

#if __has_builtin(__builtin_amdgcn_exp2f)
#define EXP2F __builtin_amdgcn_exp2f
#else
#define EXP2F exp2f
#endif

__device__ __forceinline__ u16 f2bf(float f) {
  u32 u = __builtin_bit_cast(u32, f);
  u = (u + 0x7FFFu + ((u >> 16) & 1u)) >> 16;
  return (u16)u;
}
// fast pack two fp32 -> bf16x2 (round-half-up): one v_perm
__device__ __forceinline__ u32 pack2f(float lo, float hi) {
  const u32 a = __builtin_bit_cast(u32, hi) + 0x8000u;
  const u32 b = __builtin_bit_cast(u32, lo) + 0x8000u;
  return __builtin_amdgcn_perm(a, b, 0x07060302u);
}

// ---------------------------------------------------------------------------
// Weight cast+transpose: W[K][N] fp32 -> Wt[N][K] bf16.
// ---------------------------------------------------------------------------
struct WC { const float* s; u16* d; int N; int tot; int kshift; };
struct WCP { WC w[11]; };

__global__ void wcast_k(WCP p) {
  const WC a = p.w[blockIdx.y];
  const int kmask = (1 << a.kshift) - 1;
  for (int idx = blockIdx.x * 256 + threadIdx.x; idx < a.tot; idx += gridDim.x * 256) {
    const int k = idx & kmask;
    const int n = idx >> a.kshift;
    a.d[idx] = f2bf(a.s[(size_t)k * a.N + n]);
  }
}

__global__ void xcast_k(const float* __restrict__ x, u16* __restrict__ xb, int n) {
  const int i = blockIdx.x * 256 + threadIdx.x;
  if (i < n) xb[i] = f2bf(x[i]);
}

// ---------------------------------------------------------------------------
// bf16 MFMA GEMM: C[M,N] = ((A[M,K] @ W) + bias) * oscale, epilogue act.
// 128x128 tile, BK=32, 256 thr = 4 waves, each 64x64 (4x4 of 16x16x32).
// ---------------------------------------------------------------------------
enum { EP_NONE = 0, EP_SIGMOID = 1, EP_GELU = 2 };

template <int OUTBF, int ACT>
__global__ __launch_bounds__(256) void gemm_mfma(
    const u16* __restrict__ A, int lda,
    const u16* __restrict__ Wt,
    const float* __restrict__ bias,
    void* __restrict__ Cout,
    int M, int N, int K, float oscale)
{
  __shared__ u16 As[128][32];
  __shared__ u16 Bs[128][32];
  const int tid = threadIdx.x;
  const int m0 = blockIdx.y * 128, n0 = blockIdx.x * 128;
  const int ln = tid & 15, quad = (tid >> 4) & 3, wv = tid >> 6;
  const int wm = (wv & 1) * 64, wn = (wv >> 1) * 64;
  const int sr = tid >> 1;
  const int sk = (tid & 1) * 16;

  f32x4 zf = {0.f, 0.f, 0.f, 0.f};
  f32x4 acc[4][4];
  #pragma unroll
  for (int i = 0; i < 4; i++)
    #pragma unroll
    for (int j = 0; j < 4; j++) acc[i][j] = zf;

  const short8 z8 = {0, 0, 0, 0, 0, 0, 0, 0};

  for (int k0 = 0; k0 < K; k0 += 32) {
    const int gm = m0 + sr;
    short8 a0 = z8, a1 = z8;
    if (gm < M) {
      const u16* p = A + (size_t)gm * lda + k0 + sk;
      a0 = *(const short8*)p;
      a1 = *(const short8*)(p + 8);
    }
    *(short8*)&As[sr][sk] = a0;
    *(short8*)&As[sr][sk + 8] = a1;
    {
      const u16* q = Wt + (size_t)(n0 + sr) * K + k0 + sk;
      *(short8*)&Bs[sr][sk] = *(const short8*)q;
      *(short8*)&Bs[sr][sk + 8] = *(const short8*)(q + 8);
    }
    __syncthreads();

    short8 af[4], bf[4];
    #pragma unroll
    for (int i = 0; i < 4; i++) af[i] = *(const short8*)&As[wm + i * 16 + ln][quad * 8];
    #pragma unroll
    for (int j = 0; j < 4; j++) bf[j] = *(const short8*)&Bs[wn + j * 16 + ln][quad * 8];
    #pragma unroll
    for (int i = 0; i < 4; i++)
      #pragma unroll
      for (int j = 0; j < 4; j++)
        acc[i][j] = __builtin_amdgcn_mfma_f32_16x16x32_bf16(af[i], bf[j], acc[i][j], 0, 0, 0);
    __syncthreads();
  }

  float bj[4];
  #pragma unroll
  for (int j = 0; j < 4; j++) bj[j] = bias[n0 + wn + j * 16 + ln];

  #pragma unroll
  for (int i = 0; i < 4; i++) {
    #pragma unroll
    for (int r = 0; r < 4; r++) {
      const int gm = m0 + wm + i * 16 + quad * 4 + r;
      if (gm >= M) continue;
      #pragma unroll
      for (int j = 0; j < 4; j++) {
        float v = (acc[i][j][r] + bj[j]) * oscale;
        if (ACT == EP_SIGMOID)   v = 1.f / (1.f + __expf(-v));
        else if (ACT == EP_GELU) v = 0.5f * v * (1.f + erff(v * 0.70710678118654752f));
        const size_t off = (size_t)gm * N + n0 + wn + j * 16 + ln;
        if (OUTBF) ((u16*)Cout)[off] = f2bf(v);
        else       ((float*)Cout)[off] = v;
      }
    }
  }
}

// ---------------------------------------------------------------------------
// MFMA flash attention v4.  Block = 128 thr = 2 waves, each wave 32 q rows.
// S^T = K.Q^T (softmax rows in-lane, no cross-lane ops in loop); no-max
// softmax p = exp2(s) with log2e folded into Q projection.
// LDS: unpadded rows + XOR granule swizzle -> bank-uniform b128/b64 access:
//   Ks[32][DH]  granule g' = g ^ (row & (DH/8-1))
//   Vt[DH][32]  granule g' = g ^ ((d ^ d>>3) & 3)   (spreads writes AND reads)
//   Pb[2][32][32] granule g' = g ^ (qrow & 3)
// Main loop split: full iterations carry no bounds checks; single guarded
// tail iteration (attn2: none, Tk=256).
// ---------------------------------------------------------------------------
template <int DH>
__global__ __launch_bounds__(128) void attn_mfma(
    const u16* __restrict__ Qp, const u16* __restrict__ Kp,
    const u16* __restrict__ Vp, u16* __restrict__ Op,
    int Tq, int Tk, int qbs, int kbs)
{
  constexpr int RS = Hn * DH;      // global row stride (elements)
  constexpr int MK = DH / 8 - 1;   // Ks granule mask
  constexpr int NC = DH / 32;      // score k-chunks
  constexpr int NM = DH / 16;      // output d-tiles

  __shared__ u16 Ks[32 * DH];
  __shared__ u16 Vt[DH * 32];
  __shared__ u16 Pb[2 * 32 * 32];

  const int b = blockIdx.y >> 3, h = blockIdx.y & 7;
  const int q0 = blockIdx.x * 64;
  const int tid = threadIdx.x;
  const int wv = tid >> 6;
  const int lane = tid & 63;
  const int ln = lane & 15, quad = lane >> 4;

  const u16* Qb = Qp + (size_t)b * qbs + h * DH;
  const u16* Kb = Kp + (size_t)b * kbs + h * DH;
  const u16* Vb = Vp + (size_t)b * kbs + h * DH;
  u16* Ob = Op + (size_t)b * qbs + h * DH;

  const short8 z8 = {0, 0, 0, 0, 0, 0, 0, 0};
  const f32x4 zf = {0.f, 0.f, 0.f, 0.f};

  // Q fragments (B-operand = Q^T), resident across K loop
  short8 qf[2][NC];
  #pragma unroll
  for (int qs = 0; qs < 2; qs++) {
    const int gq = q0 + wv * 32 + qs * 16 + ln;
    #pragma unroll
    for (int c = 0; c < NC; c++) {
      if (gq < Tq) qf[qs][c] = *(const short8*)(Qb + (size_t)gq * RS + c * 32 + quad * 8);
      else         qf[qs][c] = z8;
    }
  }

  f32x4 oacc[2][NM];
  float lsum[2] = {0.f, 0.f};
  #pragma unroll
  for (int qs = 0; qs < 2; qs++)
    #pragma unroll
    for (int c = 0; c < NM; c++) oacc[qs][c] = zf;

  const int nfull = Tk >> 5;
  const int nit = (Tk + 31) >> 5;

  for (int it = 0; it < nit; it++) {
    const int k0 = it << 5;
    const bool full = (it < nfull);     // wave-uniform branch
    __syncthreads();

    // ---- stage K [key][d], XOR-swizzled granules ----
    {
      const int r = tid >> 2;           // key row 0..31
      const int gk = k0 + r;
      if (DH == 64) {
        const u16* p = Kb + (size_t)gk * RS + (tid & 3) * 16;
        short8 a = z8, b2 = z8;
        if (full || gk < Tk) { a = *(const short8*)p; b2 = *(const short8*)(p + 8); }
        const int g0 = (((tid & 3) * 2) ^ (r & 7));
        const int g1 = (((tid & 3) * 2 + 1) ^ (r & 7));
        *(short8*)&Ks[r * 64 + g0 * 8] = a;
        *(short8*)&Ks[r * 64 + g1 * 8] = b2;
      } else {
        const u16* p = Kb + (size_t)gk * RS + (tid & 3) * 8;
        short8 a = z8;
        if (full || gk < Tk) a = *(const short8*)p;
        const int g0 = ((tid & 3) ^ (r & 3));
        *(short8*)&Ks[r * 32 + g0 * 8] = a;
      }
    }
    // ---- stage V transposed (reg transpose, swizzled b64 writes) ----
    {
      const int vd0 = (tid & 15) * (DH / 16);
      const int vk = (tid >> 4) * 4;
      const int gb = vk >> 3, off = vk & 7;
      short4v vrow[4];
      #pragma unroll
      for (int i2 = 0; i2 < 4; i2++) {
        const int gk = k0 + vk + i2;
        short4v t = {0, 0, 0, 0};
        if (DH == 64) {
          if (full || gk < Tk) t = *(const short4v*)(Vb + (size_t)gk * RS + vd0);
        } else {
          if (full || gk < Tk) {
            ushort2 u = *(const ushort2*)(Vb + (size_t)gk * RS + vd0);
            t[0] = (short)u.x; t[1] = (short)u.y;
          }
        }
        vrow[i2] = t;
      }
      #pragma unroll
      for (int i = 0; i < DH / 16; i++) {
        const int d = vd0 + i;
        const int h2 = (d ^ (d >> 3)) & 3;
        short4v w = {vrow[0][i], vrow[1][i], vrow[2][i], vrow[3][i]};
        *(short4v*)&Vt[d * 32 + ((gb ^ h2) << 3) + off] = w;
      }
    }
    __syncthreads();

    // ---- K fragments ----
    short8 kf[2][NC];
    #pragma unroll
    for (int kc = 0; kc < 2; kc++) {
      const int r = kc * 16 + ln;
      #pragma unroll
      for (int c = 0; c < NC; c++) {
        const int g = (4 * c + quad) ^ (r & MK);
        kf[kc][c] = *(const short8*)&Ks[r * DH + g * 8];
      }
    }

    // ---- scores S^T, exp2, pack P (swizzled b64 writes) ----
    #pragma unroll
    for (int qs = 0; qs < 2; qs++) {
      #pragma unroll
      for (int kc = 0; kc < 2; kc++) {
        f32x4 s = zf;
        #pragma unroll
        for (int c = 0; c < NC; c++)
          s = __builtin_amdgcn_mfma_f32_16x16x32_bf16(kf[kc][c], qf[qs][c], s, 0, 0, 0);
        float p0, p1, p2, p3;
        if (full) {
          p0 = EXP2F(s[0]); p1 = EXP2F(s[1]); p2 = EXP2F(s[2]); p3 = EXP2F(s[3]);
        } else {
          const int kb = k0 + kc * 16 + quad * 4;
          p0 = (kb + 0 < Tk) ? EXP2F(s[0]) : 0.f;
          p1 = (kb + 1 < Tk) ? EXP2F(s[1]) : 0.f;
          p2 = (kb + 2 < Tk) ? EXP2F(s[2]) : 0.f;
          p3 = (kb + 3 < Tk) ? EXP2F(s[3]) : 0.f;
        }
        lsum[qs] += (p0 + p1) + (p2 + p3);
        short4v pw;
        ((u32*)&pw)[0] = pack2f(p0, p1);
        ((u32*)&pw)[1] = pack2f(p2, p3);
        const int q = qs * 16 + ln;
        const int g = ((kc * 2 + (quad >> 1)) ^ (ln & 3)) & 3;
        *(short4v*)&Pb[wv * 1024 + q * 32 + (g << 3) + (quad & 1) * 4] = pw;
      }
    }

    // ---- PV: O += P.V (per-wave Pb, no barrier) ----
    short8 pf2[2];
    #pragma unroll
    for (int qs = 0; qs < 2; qs++) {
      const int q = qs * 16 + ln;
      const int g = quad ^ (ln & 3);
      pf2[qs] = *(const short8*)&Pb[wv * 1024 + q * 32 + g * 8];
    }
    #pragma unroll
    for (int c = 0; c < NM; c++) {
      const int d = c * 16 + ln;
      const int g = quad ^ ((d ^ (d >> 3)) & 3);
      const short8 vf = *(const short8*)&Vt[d * 32 + g * 8];
      #pragma unroll
      for (int qs = 0; qs < 2; qs++)
        oacc[qs][c] = __builtin_amdgcn_mfma_f32_16x16x32_bf16(pf2[qs], vf, oacc[qs][c], 0, 0, 0);
    }
  }

  // ---- epilogue: reduce l across quads, divide, store ----
  float lq[2];
  #pragma unroll
  for (int qs = 0; qs < 2; qs++) {
    float t = lsum[qs];
    t += __shfl_xor(t, 16);
    t += __shfl_xor(t, 32);
    lq[qs] = t;
  }
  #pragma unroll
  for (int qs = 0; qs < 2; qs++) {
    #pragma unroll
    for (int r = 0; r < 4; r++) {
      const float linv = 1.f / __shfl(lq[qs], quad * 4 + r);
      const int gq = q0 + wv * 32 + qs * 16 + quad * 4 + r;
      if (gq >= Tq) continue;
      #pragma unroll
      for (int c = 0; c < NM; c++)
        Ob[(size_t)gq * RS + c * 16 + ln] = f2bf(oacc[qs][c][r] * linv);
    }
  }
}

// ---------------------------------------------------------------------------
// FUSED grouped-conv (pos) + final combine (register-window sliding conv).
// ---------------------------------------------------------------------------
__global__ __launch_bounds__(256) void conv_combine(
    const float* __restrict__ x, const float* __restrict__ cw,
    const float* __restrict__ cb, const float* __restrict__ x_self,
    const float* __restrict__ x_mem, const float* __restrict__ lam,
    float* __restrict__ out)
{
  const int bh = blockIdx.x;               // b*32 + h
  const int b = bh >> 5, hh = bh & 31;
  const int c = (blockIdx.y << 8) + threadIdx.x;   // 0..511
  const int ci = c & ~1;
  const int dd = c & 63;
  const int h8 = c >> 6;
  const float alpha = 1.f / (1.f + __expf(-lam[h8]));
  const float bias = cb[c];

  float wgt[2][9];
  #pragma unroll
  for (int ch = 0; ch < 2; ch++)
    #pragma unroll
    for (int k = 0; k < 9; k++) wgt[ch][k] = cw[c * 18 + ch * 9 + k];

  const float* xrow[3];
  bool rv[3];
  #pragma unroll
  for (int r = 0; r < 3; r++) {
    const int h2 = hh + r - 1;
    rv[r] = (unsigned)h2 < 32u;
    xrow[r] = x + ((size_t)(b * Tt) + 1 + h2 * 32) * Cc + ci;
  }

  float2 win[3][3];
  #pragma unroll
  for (int r = 0; r < 3; r++) {
    win[r][0] = make_float2(0.f, 0.f);
    win[r][1] = rv[r] ? *(const float2*)(xrow[r]) : make_float2(0.f, 0.f);
  }

  const size_t bT = (size_t)b * Tt;
  for (int w = 0; w < 32; w++) {
    #pragma unroll
    for (int r = 0; r < 3; r++)
      win[r][2] = (rv[r] && w + 1 < 32) ? *(const float2*)(xrow[r] + (w + 1) * Cc)
                                        : make_float2(0.f, 0.f);
    float pos = bias;
    #pragma unroll
    for (int r = 0; r < 3; r++)
      #pragma unroll
      for (int col = 0; col < 3; col++) {
        pos += win[r][col].x * wgt[0][r * 3 + col];
        pos += win[r][col].y * wgt[1][r * 3 + col];
      }
    const size_t bt = bT + 1 + hh * 32 + w;
    const float mem = (dd < 32) ? x_mem[bt * 256 + h8 * 32 + dd] : 0.f;
    out[bt * 512 + c] = pos + alpha * mem + (1.f - alpha) * x_self[bt * 512 + c];
    #pragma unroll
    for (int r = 0; r < 3; r++) { win[r][0] = win[r][1]; win[r][1] = win[r][2]; }
  }

  if (hh == 0) {
    const float mem = (dd < 32) ? x_mem[bT * 256 + h8 * 32 + dd] : 0.f;
    out[bT * 512 + c] = alpha * mem + (1.f - alpha) * x_self[bT * 512 + c];
  }
}

// cat = [gr (bcast) | x_summary] bf16
__global__ void build_cat(const float* __restrict__ gr_cache,
                          const float* __restrict__ x_self,
                          u16* __restrict__ cat)
{
  const int idx = blockIdx.x * 256 + threadIdx.x;
  if (idx >= Bc * Ll * 512) return;
  const int k = idx & 511;
  const int bi = idx >> 9;
  const int i = bi & 255;
  const int b = bi >> 8;
  float v;
  if (k < 256) v = gr_cache[i * 256 + k];
  else         v = x_self[((size_t)(b * Tt + 4 * i)) * Cc + (k - 256)];
  cat[idx] = f2bf(v);
}

// cat[:, :256] = bf16(reset * gr)
__global__ void build_cat2(const float* __restrict__ gr_cache,
                           const float* __restrict__ reset,
                           u16* __restrict__ cat)
{
  const int idx = blockIdx.x * 256 + threadIdx.x;
  if (idx >= Bc * Ll * 256) return;
  const int k = idx & 255;
  const int bi = idx >> 8;
  const int i = bi & 255;
  cat[(size_t)bi * 512 + k] = f2bf(gr_cache[i * 256 + k] * reset[idx]);
}

// LayerNorm + gate -> gr_new bf16
__device__ inline float block_sum256(float v, float* red)
{
  #pragma unroll
  for (int o = 32; o >= 1; o >>= 1) v += __shfl_down(v, o);
  const int wid = threadIdx.x >> 6;
  if ((threadIdx.x & 63) == 0) red[wid] = v;
  __syncthreads();
  const float t = red[0] + red[1] + red[2] + red[3];
  __syncthreads();
  return t;
}

__global__ __launch_bounds__(256) void ln_gate(
    const float* __restrict__ add_raw, const float* __restrict__ z,
    const float* __restrict__ gr_cache, const float* __restrict__ gamma,
    const float* __restrict__ beta, u16* __restrict__ gr_new)
{
  __shared__ float red[4];
  const int bi = blockIdx.x;
  const int i = bi & 255;
  const int c = threadIdx.x;
  const float v = add_raw[(size_t)bi * 256 + c];
  const float mu = block_sum256(v, red) * (1.f / 256.f);
  const float dv = v - mu;
  const float var = block_sum256(dv * dv, red) * (1.f / 256.f);
  const float nrm = dv * rsqrtf(var + 1e-5f) * gamma[c] + beta[c];
  const float zz = z[(size_t)bi * 256 + c];
  gr_new[(size_t)bi * 256 + c] = f2bf(zz * nrm + (1.f - zz) * gr_cache[i * 256 + c]);
}

// ---------------------------------------------------------------------------
extern "C" void kernel_launch(void* const* d_in, const int* in_sizes, int n_in,
                              void* d_out, int out_size, void* d_ws, size_t ws_size,
                              hipStream_t stream)
{
  const float* x        = (const float*)d_in[0];
  const float* gr_cache = (const float*)d_in[1];
  const float* Wq1 = (const float*)d_in[2];  const float* bq1 = (const float*)d_in[3];
  const float* Wk1 = (const float*)d_in[4];  const float* bk1 = (const float*)d_in[5];
  const float* Wv1 = (const float*)d_in[6];  const float* bv1 = (const float*)d_in[7];
  const float* Wo1 = (const float*)d_in[8];  const float* bo1 = (const float*)d_in[9];
  const float* Wq2 = (const float*)d_in[10]; const float* bq2 = (const float*)d_in[11];
  const float* Wk2 = (const float*)d_in[12]; const float* bk2 = (const float*)d_in[13];
  const float* Wv2 = (const float*)d_in[14]; const float* bv2 = (const float*)d_in[15];
  const float* Wo2 = (const float*)d_in[16]; const float* bo2 = (const float*)d_in[17];
  const float* Wr  = (const float*)d_in[18]; const float* br  = (const float*)d_in[19];
  const float* Wz  = (const float*)d_in[20]; const float* bz  = (const float*)d_in[21];
  const float* Wa  = (const float*)d_in[22]; const float* ba  = (const float*)d_in[23];
  const float* gamma = (const float*)d_in[24];
  const float* beta  = (const float*)d_in[25];
  const float* lam   = (const float*)d_in[26];
  const float* conv_w = (const float*)d_in[27];
  const float* conv_b = (const float*)d_in[28];
  float* out = (float*)d_out;

  const int M1 = Bc * Tt;       // 8200
  const int M2 = Bc * Ll;       // 2048
  const size_t BTC = (size_t)Bc * Tt * Cc;    // 4,198,400
  const size_t BLA = (size_t)Bc * Ll * CA;
  const size_t BL2 = (size_t)Bc * Ll * 512;

  char* W = (char*)d_ws;
  // phase-1 layout (bytes)
  u16*   xb     = (u16*)(W + 0);                       // 8,396,800 B
  u16*   q1     = (u16*)(W + 8396800);
  u16*   k1     = (u16*)(W + 16793600);
  u16*   v1     = (u16*)(W + 25190400);
  u16*   att1   = (u16*)(W + 33587200);
  float* x_self = (float*)(W + 41984000);              // 16,793,600 B
  u16*   wtb    = (u16*)(W + 58777600);                // 3,407,872 B
  // phase-2 overlay (q1/k1/v1 region dead by then)
  u16*   cat    = (u16*)(W + 8396800);
  float* rg     = (float*)(W + 10493952);
  float* zg     = (float*)(W + 12591104);
  float* addr_  = (float*)(W + 14688256);
  u16*   gr_new = (u16*)(W + 16785408);
  u16*   k2     = (u16*)(W + 17833984);
  u16*   v2     = (u16*)(W + 18882560);
  u16*   q2     = (u16*)(W + 19931136);
  u16*   att2   = (u16*)(W + 24129536);
  float* x_mem  = (float*)(W + 28327936);

  u16* Wq1t = wtb + 0;       u16* Wk1t = wtb + 262144;  u16* Wv1t = wtb + 524288;
  u16* Wo1t = wtb + 786432;  u16* Wrt  = wtb + 1048576; u16* Wzt  = wtb + 1179648;
  u16* Wat  = wtb + 1310720; u16* Wq2t = wtb + 1441792; u16* Wk2t = wtb + 1507328;
  u16* Wv2t = wtb + 1572864; u16* Wo2t = wtb + 1638400;

  const dim3 blk(256);
  const int ew_btc = (int)((BTC + 255) / 256);

  // ---- casts ----
  {
    WCP p;
    const float* ws_[11] = {Wq1, Wk1, Wv1, Wo1, Wr, Wz, Wa, Wq2, Wk2, Wv2, Wo2};
    u16* wd_[11] = {Wq1t, Wk1t, Wv1t, Wo1t, Wrt, Wzt, Wat, Wq2t, Wk2t, Wv2t, Wo2t};
    const int Kk[11] = {512,512,512,512,512,512,512,256,256,256,256};
    const int Nn[11] = {512,512,512,512,256,256,256,256,256,256,256};
    for (int i = 0; i < 11; i++) {
      p.w[i].s = ws_[i]; p.w[i].d = wd_[i]; p.w[i].N = Nn[i];
      p.w[i].tot = Kk[i] * Nn[i];
      p.w[i].kshift = (Kk[i] == 512) ? 9 : 8;
    }
    wcast_k<<<dim3(64, 11), blk, 0, stream>>>(p);
  }
  xcast_k<<<ew_btc, blk, 0, stream>>>(x, xb, (int)BTC);

  // ---- MHA1 ----  (softmax scale * log2(e) folded into Q projection)
  const dim3 g512(4, 65), g256m1(2, 65), g256m2(2, 16);
  gemm_mfma<1, EP_NONE><<<g512, blk, 0, stream>>>(xb, 512, Wq1t, bq1, q1, M1, 512, 512,
                                                  0.18033688011112042f);
  gemm_mfma<1, EP_NONE><<<g512, blk, 0, stream>>>(xb, 512, Wk1t, bk1, k1, M1, 512, 512, 1.f);
  gemm_mfma<1, EP_NONE><<<g512, blk, 0, stream>>>(xb, 512, Wv1t, bv1, v1, M1, 512, 512, 1.f);
  attn_mfma<64><<<dim3(17, 64), dim3(128), 0, stream>>>(q1, k1, v1, att1, Tt, Tt,
                                                        Tt * 512, Tt * 512);
  gemm_mfma<0, EP_NONE><<<g512, blk, 0, stream>>>(att1, 512, Wo1t, bo1, x_self, M1, 512, 512, 1.f);

  // ---- GRU cache update ----
  build_cat<<<(int)((BL2 + 255) / 256), blk, 0, stream>>>(gr_cache, x_self, cat);
  gemm_mfma<0, EP_SIGMOID><<<g256m2, blk, 0, stream>>>(cat, 512, Wrt, br, rg, M2, 256, 512, 1.f);
  gemm_mfma<0, EP_SIGMOID><<<g256m2, blk, 0, stream>>>(cat, 512, Wzt, bz, zg, M2, 256, 512, 1.f);
  build_cat2<<<(int)((BLA + 255) / 256), blk, 0, stream>>>(gr_cache, rg, cat);
  gemm_mfma<0, EP_GELU><<<g256m2, blk, 0, stream>>>(cat, 512, Wat, ba, addr_, M2, 256, 512, 1.f);
  ln_gate<<<M2, blk, 0, stream>>>(addr_, zg, gr_cache, gamma, beta, gr_new);

  // ---- MHA2 ----
  gemm_mfma<1, EP_NONE><<<g256m1, blk, 0, stream>>>(xb, 512, Wq2t, bq2, q2, M1, 256, 256,
                                                    0.25503490664918414f);
  gemm_mfma<1, EP_NONE><<<g256m2, blk, 0, stream>>>(gr_new, 256, Wk2t, bk2, k2, M2, 256, 256, 1.f);
  gemm_mfma<1, EP_NONE><<<g256m2, blk, 0, stream>>>(gr_new, 256, Wv2t, bv2, v2, M2, 256, 256, 1.f);
  attn_mfma<32><<<dim3(17, 64), dim3(128), 0, stream>>>(q2, k2, v2, att2, Tt, Ll,
                                                        Tt * 256, Ll * 256);
  gemm_mfma<0, EP_NONE><<<g256m1, blk, 0, stream>>>(att2, 256, Wo2t, bo2, x_mem, M1, 256, 256, 1.f);

  // ---- fused conv(pos) + final mix -> d_out ----
  conv_combine<<<dim3(Bc * 32, 2), blk, 0, stream>>>(x, conv_w, conv_b, x_self,
                                                     x_mem, lam, out);
}

// Round 7
// 370.287 us; speedup vs baseline: 4.0352x; 1.0728x over previous
//
#include <hip/hip_runtime.h>
#include <math.h>

typedef unsigned short u16;
typedef unsigned int u32;
typedef __attribute__((ext_vector_type(8))) short short8;
typedef __attribute__((ext_vector_type(4))) short short4v;
typedef __attribute__((ext_vector_type(4))) float f32x4;

// Problem constants
constexpr int Bc = 8;
constexpr int Tt = 1025;
constexpr int Cc = 512;
constexpr int Hn = 8;
constexpr int CA = 256;
constexpr int Ll = 256;

#if __has_builtin(__builtin_amdgcn_exp2f)
#define EXP2F __builtin_amdgcn_exp2f
#else
#define EXP2F exp2f
#endif

__device__ __forceinline__ u16 f2bf(float f) {
  u32 u = __builtin_bit_cast(u32, f);
  u = (u + 0x7FFFu + ((u >> 16) & 1u)) >> 16;
  return (u16)u;
}
// fast pack two fp32 -> bf16x2 (round-half-up): one v_perm
__device__ __forceinline__ u32 pack2f(float lo, float hi) {
  const u32 a = __builtin_bit_cast(u32, hi) + 0x8000u;
  const u32 b = __builtin_bit_cast(u32, lo) + 0x8000u;
  return __builtin_amdgcn_perm(a, b, 0x07060302u);
}

// ---------------------------------------------------------------------------
// Weight cast+transpose into fused layouts: dst[n][k] = k<sK ? W[k][n] : 0
// dst row length dK (pow2). One y-block per weight.
// ---------------------------------------------------------------------------
struct WC { const float* s; u16* d; int sN; int sK; int kshift; int tot; };
struct WCP { WC w[11]; };

__global__ void wcast_k(WCP p) {
  const WC a = p.w[blockIdx.y];
  const int kmask = (1 << a.kshift) - 1;
  for (int idx = blockIdx.x * 256 + threadIdx.x; idx < a.tot; idx += gridDim.x * 256) {
    const int k = idx & kmask;
    const int n = idx >> a.kshift;
    a.d[idx] = (k < a.sK) ? f2bf(a.s[(size_t)k * a.sN + n]) : (u16)0;
  }
}

// ---------------------------------------------------------------------------
// bf16 MFMA GEMM with per-column-region bias/scale map.
// C[M,N] = act((A@W + bias[region]) * scale[region]).
// A is bf16 (AF32=0) or fp32 with on-the-fly bf16 cast in staging (AF32=1).
// 128x128 tile, BK=32, 256 thr = 4 waves, each 64x64 (4x4 of 16x16x32).
// Region boundaries must be multiples of 128 (tile-uniform).
// ---------------------------------------------------------------------------
enum { EP_NONE = 0, EP_SIGMOID = 1, EP_GELU = 2 };

struct GemmEpi {
  const float* bias[4];
  int start[4];
  float scale[4];
  int nreg;
};

template <int AF32, int OUTBF, int ACT>
__global__ __launch_bounds__(256) void gemm_mfma(
    const void* __restrict__ Av, int lda,
    const u16* __restrict__ Wt,
    GemmEpi epi,
    void* __restrict__ Cout,
    int M, int N, int K)
{
  __shared__ u16 As[128][32];
  __shared__ u16 Bs[128][32];
  const int tid = threadIdx.x;
  const int m0 = blockIdx.y * 128, n0 = blockIdx.x * 128;
  const int ln = tid & 15, quad = (tid >> 4) & 3, wv = tid >> 6;
  const int wm = (wv & 1) * 64, wn = (wv >> 1) * 64;
  const int sr = tid >> 1;
  const int sk = (tid & 1) * 16;

  f32x4 zf = {0.f, 0.f, 0.f, 0.f};
  f32x4 acc[4][4];
  #pragma unroll
  for (int i = 0; i < 4; i++)
    #pragma unroll
    for (int j = 0; j < 4; j++) acc[i][j] = zf;

  const short8 z8 = {0, 0, 0, 0, 0, 0, 0, 0};

  for (int k0 = 0; k0 < K; k0 += 32) {
    const int gm = m0 + sr;
    short8 a0 = z8, a1 = z8;
    if (gm < M) {
      if (AF32) {
        const float* p = (const float*)Av + (size_t)gm * lda + k0 + sk;
        const float4 f0 = *(const float4*)(p + 0);
        const float4 f1 = *(const float4*)(p + 4);
        const float4 f2 = *(const float4*)(p + 8);
        const float4 f3 = *(const float4*)(p + 12);
        ((u32*)&a0)[0] = pack2f(f0.x, f0.y);
        ((u32*)&a0)[1] = pack2f(f0.z, f0.w);
        ((u32*)&a0)[2] = pack2f(f1.x, f1.y);
        ((u32*)&a0)[3] = pack2f(f1.z, f1.w);
        ((u32*)&a1)[0] = pack2f(f2.x, f2.y);
        ((u32*)&a1)[1] = pack2f(f2.z, f2.w);
        ((u32*)&a1)[2] = pack2f(f3.x, f3.y);
        ((u32*)&a1)[3] = pack2f(f3.z, f3.w);
      } else {
        const u16* p = (const u16*)Av + (size_t)gm * lda + k0 + sk;
        a0 = *(const short8*)p;
        a1 = *(const short8*)(p + 8);
      }
    }
    *(short8*)&As[sr][sk] = a0;
    *(short8*)&As[sr][sk + 8] = a1;
    {
      const u16* q = Wt + (size_t)(n0 + sr) * K + k0 + sk;
      *(short8*)&Bs[sr][sk] = *(const short8*)q;
      *(short8*)&Bs[sr][sk + 8] = *(const short8*)(q + 8);
    }
    __syncthreads();

    short8 af[4], bf[4];
    #pragma unroll
    for (int i = 0; i < 4; i++) af[i] = *(const short8*)&As[wm + i * 16 + ln][quad * 8];
    #pragma unroll
    for (int j = 0; j < 4; j++) bf[j] = *(const short8*)&Bs[wn + j * 16 + ln][quad * 8];
    #pragma unroll
    for (int i = 0; i < 4; i++)
      #pragma unroll
      for (int j = 0; j < 4; j++)
        acc[i][j] = __builtin_amdgcn_mfma_f32_16x16x32_bf16(af[i], bf[j], acc[i][j], 0, 0, 0);
    __syncthreads();
  }

  // region select (uniform per block: boundaries are 128-multiples)
  int ri = 0;
  #pragma unroll
  for (int i = 1; i < 4; i++)
    if (i < epi.nreg && epi.start[i] <= n0) ri = i;
  const float* bp = epi.bias[ri] - epi.start[ri];
  const float sc = epi.scale[ri];

  float bj[4];
  #pragma unroll
  for (int j = 0; j < 4; j++) bj[j] = bp[n0 + wn + j * 16 + ln];

  #pragma unroll
  for (int i = 0; i < 4; i++) {
    #pragma unroll
    for (int r = 0; r < 4; r++) {
      const int gm = m0 + wm + i * 16 + quad * 4 + r;
      if (gm >= M) continue;
      #pragma unroll
      for (int j = 0; j < 4; j++) {
        float v = (acc[i][j][r] + bj[j]) * sc;
        if (ACT == EP_SIGMOID)   v = 1.f / (1.f + __expf(-v));
        else if (ACT == EP_GELU) v = 0.5f * v * (1.f + erff(v * 0.70710678118654752f));
        const size_t off = (size_t)gm * N + n0 + wn + j * 16 + ln;
        if (OUTBF) ((u16*)Cout)[off] = f2bf(v);
        else       ((float*)Cout)[off] = v;
      }
    }
  }
}

// ---------------------------------------------------------------------------
// MFMA flash attention v5.  Block = 128 thr = 2 waves, each wave 32 q rows.
// S^T = K.Q^T; no-max softmax p = exp2(s), scale*log2e folded into Q proj.
// K fragments loaded DIRECTLY from global (L1/L2-served) -> no Ks LDS tile.
// Vt double-buffered -> ONE barrier per iteration.
// Strides are runtime args so Q/K/V can live inside fused GEMM outputs.
// ---------------------------------------------------------------------------
template <int DH>
__global__ __launch_bounds__(128) void attn_mfma(
    const u16* __restrict__ Qp, const u16* __restrict__ Kp,
    const u16* __restrict__ Vp, u16* __restrict__ Op,
    int Tq, int Tk, int qbs, int kbs, int obs, int qrs, int krs, int ors)
{
  constexpr int NC = DH / 32;      // score k-chunks
  constexpr int NM = DH / 16;      // output d-tiles

  __shared__ u16 Vt[2][DH * 32];
  __shared__ u16 Pb[2 * 32 * 32];

  const int b = blockIdx.y >> 3, h = blockIdx.y & 7;
  const int q0 = blockIdx.x * 64;
  const int tid = threadIdx.x;
  const int wv = tid >> 6;
  const int lane = tid & 63;
  const int ln = lane & 15, quad = lane >> 4;

  const u16* Qb = Qp + (size_t)b * qbs + h * DH;
  const u16* Kb = Kp + (size_t)b * kbs + h * DH;
  const u16* Vb = Vp + (size_t)b * kbs + h * DH;
  u16* Ob = Op + (size_t)b * obs + h * DH;

  const short8 z8 = {0, 0, 0, 0, 0, 0, 0, 0};
  const f32x4 zf = {0.f, 0.f, 0.f, 0.f};

  // Q fragments (B-operand = Q^T), resident across K loop
  short8 qf[2][NC];
  #pragma unroll
  for (int qs = 0; qs < 2; qs++) {
    const int gq = q0 + wv * 32 + qs * 16 + ln;
    #pragma unroll
    for (int c = 0; c < NC; c++) {
      if (gq < Tq) qf[qs][c] = *(const short8*)(Qb + (size_t)gq * qrs + c * 32 + quad * 8);
      else         qf[qs][c] = z8;
    }
  }

  f32x4 oacc[2][NM];
  float lsum[2] = {0.f, 0.f};
  #pragma unroll
  for (int qs = 0; qs < 2; qs++)
    #pragma unroll
    for (int c = 0; c < NM; c++) oacc[qs][c] = zf;

  // V staging maps
  const int vd0 = (tid & 15) * (DH / 16);
  const int vk = (tid >> 4) * 4;
  const int gb = vk >> 3, off = vk & 7;

  const int nfull = Tk >> 5;
  const int nit = (Tk + 31) >> 5;

  for (int it = 0; it < nit; it++) {
    const int k0 = it << 5;
    const bool full = (it < nfull);     // wave-uniform
    u16* vt = &Vt[it & 1][0];

    // ---- K fragments straight from global (issue first: overlaps staging) ----
    short8 kf[2][NC];
    if (full) {
      #pragma unroll
      for (int kc = 0; kc < 2; kc++)
        #pragma unroll
        for (int c = 0; c < NC; c++)
          kf[kc][c] = *(const short8*)(Kb + (size_t)(k0 + kc * 16 + ln) * krs
                                          + c * 32 + quad * 8);
    } else {
      #pragma unroll
      for (int kc = 0; kc < 2; kc++)
        #pragma unroll
        for (int c = 0; c < NC; c++) {
          const int row = k0 + kc * 16 + ln;
          kf[kc][c] = (row < Tk)
              ? *(const short8*)(Kb + (size_t)row * krs + c * 32 + quad * 8)
              : z8;
        }
    }

    // ---- stage V transposed into Vt[it&1] (reg transpose, swizzled b64) ----
    {
      short4v vrow[4];
      #pragma unroll
      for (int i2 = 0; i2 < 4; i2++) {
        const int gk = k0 + vk + i2;
        short4v t = {0, 0, 0, 0};
        if (DH == 64) {
          if (full || gk < Tk) t = *(const short4v*)(Vb + (size_t)gk * krs + vd0);
        } else {
          if (full || gk < Tk) {
            ushort2 u = *(const ushort2*)(Vb + (size_t)gk * krs + vd0);
            t[0] = (short)u.x; t[1] = (short)u.y;
          }
        }
        vrow[i2] = t;
      }
      #pragma unroll
      for (int i = 0; i < DH / 16; i++) {
        const int d = vd0 + i;
        const int h2 = (d ^ (d >> 3)) & 3;
        short4v w = {vrow[0][i], vrow[1][i], vrow[2][i], vrow[3][i]};
        *(short4v*)&vt[d * 32 + ((gb ^ h2) << 3) + off] = w;
      }
    }
    __syncthreads();   // single barrier per iter (Vt dbuf)

    // ---- scores S^T, exp2, pack P (swizzled b64 writes) ----
    #pragma unroll
    for (int qs = 0; qs < 2; qs++) {
      #pragma unroll
      for (int kc = 0; kc < 2; kc++) {
        f32x4 s = zf;
        #pragma unroll
        for (int c = 0; c < NC; c++)
          s = __builtin_amdgcn_mfma_f32_16x16x32_bf16(kf[kc][c], qf[qs][c], s, 0, 0, 0);
        float p0, p1, p2, p3;
        if (full) {
          p0 = EXP2F(s[0]); p1 = EXP2F(s[1]); p2 = EXP2F(s[2]); p3 = EXP2F(s[3]);
        } else {
          const int kb = k0 + kc * 16 + quad * 4;
          p0 = (kb + 0 < Tk) ? EXP2F(s[0]) : 0.f;
          p1 = (kb + 1 < Tk) ? EXP2F(s[1]) : 0.f;
          p2 = (kb + 2 < Tk) ? EXP2F(s[2]) : 0.f;
          p3 = (kb + 3 < Tk) ? EXP2F(s[3]) : 0.f;
        }
        lsum[qs] += (p0 + p1) + (p2 + p3);
        short4v pw;
        ((u32*)&pw)[0] = pack2f(p0, p1);
        ((u32*)&pw)[1] = pack2f(p2, p3);
        const int q = qs * 16 + ln;
        const int g = ((kc * 2 + (quad >> 1)) ^ (ln & 3)) & 3;
        *(short4v*)&Pb[wv * 1024 + q * 32 + (g << 3) + (quad & 1) * 4] = pw;
      }
    }

    // ---- PV: O += P.V (per-wave Pb, no barrier) ----
    short8 pf2[2];
    #pragma unroll
    for (int qs = 0; qs < 2; qs++) {
      const int q = qs * 16 + ln;
      const int g = quad ^ (ln & 3);
      pf2[qs] = *(const short8*)&Pb[wv * 1024 + q * 32 + g * 8];
    }
    #pragma unroll
    for (int c = 0; c < NM; c++) {
      const int d = c * 16 + ln;
      const int g = quad ^ ((d ^ (d >> 3)) & 3);
      const short8 vf = *(const short8*)&vt[d * 32 + g * 8];
      #pragma unroll
      for (int qs = 0; qs < 2; qs++)
        oacc[qs][c] = __builtin_amdgcn_mfma_f32_16x16x32_bf16(pf2[qs], vf, oacc[qs][c], 0, 0, 0);
    }
  }

  // ---- epilogue: reduce l across quads, divide, store ----
  float lq[2];
  #pragma unroll
  for (int qs = 0; qs < 2; qs++) {
    float t = lsum[qs];
    t += __shfl_xor(t, 16);
    t += __shfl_xor(t, 32);
    lq[qs] = t;
  }
  #pragma unroll
  for (int qs = 0; qs < 2; qs++) {
    #pragma unroll
    for (int r = 0; r < 4; r++) {
      const float linv = 1.f / __shfl(lq[qs], quad * 4 + r);
      const int gq = q0 + wv * 32 + qs * 16 + quad * 4 + r;
      if (gq >= Tq) continue;
      #pragma unroll
      for (int c = 0; c < NM; c++)
        Ob[(size_t)gq * ors + c * 16 + ln] = f2bf(oacc[qs][c][r] * linv);
    }
  }
}

// ---------------------------------------------------------------------------
// FUSED grouped-conv (pos) + final combine (register-window sliding conv).
// ---------------------------------------------------------------------------
__global__ __launch_bounds__(256) void conv_combine(
    const float* __restrict__ x, const float* __restrict__ cw,
    const float* __restrict__ cb, const float* __restrict__ x_self,
    const float* __restrict__ x_mem, const float* __restrict__ lam,
    float* __restrict__ out)
{
  const int bh = blockIdx.x;               // b*32 + h
  const int b = bh >> 5, hh = bh & 31;
  const int c = (blockIdx.y << 8) + threadIdx.x;   // 0..511
  const int ci = c & ~1;
  const int dd = c & 63;
  const int h8 = c >> 6;
  const float alpha = 1.f / (1.f + __expf(-lam[h8]));
  const float bias = cb[c];

  float wgt[2][9];
  #pragma unroll
  for (int ch = 0; ch < 2; ch++)
    #pragma unroll
    for (int k = 0; k < 9; k++) wgt[ch][k] = cw[c * 18 + ch * 9 + k];

  const float* xrow[3];
  bool rv[3];
  #pragma unroll
  for (int r = 0; r < 3; r++) {
    const int h2 = hh + r - 1;
    rv[r] = (unsigned)h2 < 32u;
    xrow[r] = x + ((size_t)(b * Tt) + 1 + h2 * 32) * Cc + ci;
  }

  float2 win[3][3];
  #pragma unroll
  for (int r = 0; r < 3; r++) {
    win[r][0] = make_float2(0.f, 0.f);
    win[r][1] = rv[r] ? *(const float2*)(xrow[r]) : make_float2(0.f, 0.f);
  }

  const size_t bT = (size_t)b * Tt;
  for (int w = 0; w < 32; w++) {
    #pragma unroll
    for (int r = 0; r < 3; r++)
      win[r][2] = (rv[r] && w + 1 < 32) ? *(const float2*)(xrow[r] + (w + 1) * Cc)
                                        : make_float2(0.f, 0.f);
    float pos = bias;
    #pragma unroll
    for (int r = 0; r < 3; r++)
      #pragma unroll
      for (int col = 0; col < 3; col++) {
        pos += win[r][col].x * wgt[0][r * 3 + col];
        pos += win[r][col].y * wgt[1][r * 3 + col];
      }
    const size_t bt = bT + 1 + hh * 32 + w;
    const float mem = (dd < 32) ? x_mem[bt * 256 + h8 * 32 + dd] : 0.f;
    out[bt * 512 + c] = pos + alpha * mem + (1.f - alpha) * x_self[bt * 512 + c];
    #pragma unroll
    for (int r = 0; r < 3; r++) { win[r][0] = win[r][1]; win[r][1] = win[r][2]; }
  }

  if (hh == 0) {
    const float mem = (dd < 32) ? x_mem[bT * 256 + h8 * 32 + dd] : 0.f;
    out[bT * 512 + c] = alpha * mem + (1.f - alpha) * x_self[bT * 512 + c];
  }
}

// cat = [gr (bcast) | x_summary] bf16
__global__ void build_cat(const float* __restrict__ gr_cache,
                          const float* __restrict__ x_self,
                          u16* __restrict__ cat)
{
  const int idx = blockIdx.x * 256 + threadIdx.x;
  if (idx >= Bc * Ll * 512) return;
  const int k = idx & 511;
  const int bi = idx >> 9;
  const int i = bi & 255;
  const int b = bi >> 8;
  float v;
  if (k < 256) v = gr_cache[i * 256 + k];
  else         v = x_self[((size_t)(b * Tt + 4 * i)) * Cc + (k - 256)];
  cat[idx] = f2bf(v);
}

// cat[:, :256] = bf16(reset * gr); reset = rzg cols 0..255
__global__ void build_cat2(const float* __restrict__ gr_cache,
                           const float* __restrict__ rzg,
                           u16* __restrict__ cat)
{
  const int idx = blockIdx.x * 256 + threadIdx.x;
  if (idx >= Bc * Ll * 256) return;
  const int k = idx & 255;
  const int bi = idx >> 8;
  const int i = bi & 255;
  cat[(size_t)bi * 512 + k] = f2bf(gr_cache[i * 256 + k] * rzg[(size_t)bi * 512 + k]);
}

// LayerNorm + gate -> gr_new bf16 ; z = rzg cols 256..511
__device__ inline float block_sum256(float v, float* red)
{
  #pragma unroll
  for (int o = 32; o >= 1; o >>= 1) v += __shfl_down(v, o);
  const int wid = threadIdx.x >> 6;
  if ((threadIdx.x & 63) == 0) red[wid] = v;
  __syncthreads();
  const float t = red[0] + red[1] + red[2] + red[3];
  __syncthreads();
  return t;
}

__global__ __launch_bounds__(256) void ln_gate(
    const float* __restrict__ add_raw, const float* __restrict__ rzg,
    const float* __restrict__ gr_cache, const float* __restrict__ gamma,
    const float* __restrict__ beta, u16* __restrict__ gr_new)
{
  __shared__ float red[4];
  const int bi = blockIdx.x;
  const int i = bi & 255;
  const int c = threadIdx.x;
  const float v = add_raw[(size_t)bi * 256 + c];
  const float mu = block_sum256(v, red) * (1.f / 256.f);
  const float dv = v - mu;
  const float var = block_sum256(dv * dv, red) * (1.f / 256.f);
  const float nrm = dv * rsqrtf(var + 1e-5f) * gamma[c] + beta[c];
  const float zz = rzg[(size_t)bi * 512 + 256 + c];
  gr_new[(size_t)bi * 256 + c] = f2bf(zz * nrm + (1.f - zz) * gr_cache[i * 256 + c]);
}

// ---------------------------------------------------------------------------
extern "C" void kernel_launch(void* const* d_in, const int* in_sizes, int n_in,
                              void* d_out, int out_size, void* d_ws, size_t ws_size,
                              hipStream_t stream)
{
  const float* x        = (const float*)d_in[0];
  const float* gr_cache = (const float*)d_in[1];
  const float* Wq1 = (const float*)d_in[2];  const float* bq1 = (const float*)d_in[3];
  const float* Wk1 = (const float*)d_in[4];  const float* bk1 = (const float*)d_in[5];
  const float* Wv1 = (const float*)d_in[6];  const float* bv1 = (const float*)d_in[7];
  const float* Wo1 = (const float*)d_in[8];  const float* bo1 = (const float*)d_in[9];
  const float* Wq2 = (const float*)d_in[10]; const float* bq2 = (const float*)d_in[11];
  const float* Wk2 = (const float*)d_in[12]; const float* bk2 = (const float*)d_in[13];
  const float* Wv2 = (const float*)d_in[14]; const float* bv2 = (const float*)d_in[15];
  const float* Wo2 = (const float*)d_in[16]; const float* bo2 = (const float*)d_in[17];
  const float* Wr  = (const float*)d_in[18]; const float* br  = (const float*)d_in[19];
  const float* Wz  = (const float*)d_in[20]; const float* bz  = (const float*)d_in[21];
  const float* Wa  = (const float*)d_in[22]; const float* ba  = (const float*)d_in[23];
  const float* gamma = (const float*)d_in[24];
  const float* beta  = (const float*)d_in[25];
  const float* lam   = (const float*)d_in[26];
  const float* conv_w = (const float*)d_in[27];
  const float* conv_b = (const float*)d_in[28];
  float* out = (float*)d_out;

  const int M1 = Bc * Tt;       // 8200
  const int M2 = Bc * Ll;       // 2048
  const size_t BTC = (size_t)Bc * Tt * Cc;
  const size_t BLA = (size_t)Bc * Ll * CA;
  const size_t BL2 = (size_t)Bc * Ll * 512;

  char* W = (char*)d_ws;
  // layout (bytes); ws >= 84 MB (R1 used that much)
  u16*   qkvq  = (u16*)(W + 0);           // [8200][1792] = 29,388,800 B
  u16*   att1  = (u16*)(W + 29388800);    // [8200][512]  =  8,396,800 B
  u16*   att2  = (u16*)(W + 29388800);    // reuse (att1 dead after o1): 4,198,400
  float* x_self= (float*)(W + 37785600);  // [8200][512] f32 = 16,793,600
  u16*   cat   = (u16*)(W + 54579200);    // [2048][512] = 2,097,152
  float* rzg   = (float*)(W + 56676352);  // [2048][512] f32 = 4,194,304
  float* addr_ = (float*)(W + 60870656);  // [2048][256] f32 = 2,097,152
  float* x_mem = (float*)(W + 54579200);  // reuse cat/rzg/addr after ln_gate: 8,396,800
  u16*   gr_new= (u16*)(W + 62976000);    // [2048][256] = 1,048,576
  u16*   k2v2  = (u16*)(W + 64024576);    // [2048][512] = 2,097,152
  u16*   wtb   = (u16*)(W + 66121728);    // 3,538,944 B -> end 69,660,672

  u16* megaW = wtb;                 // [1792][512]
  u16* o1W   = wtb + 917504;        // [512][512]
  u16* rzW   = wtb + 1179648;       // [512][512]
  u16* aW    = wtb + 1441792;       // [256][512]
  u16* kvW   = wtb + 1572864;       // [512][256]
  u16* o2W   = wtb + 1703936;       // [256][256]

  const dim3 blk(256);

  // ---- weight casts into fused layouts ----
  {
    WCP p;
    // {src, dst, sN, sK, kshift(dK)}
    p.w[0]  = {Wq1, megaW + 0,           512, 512, 9, 512 * 512};
    p.w[1]  = {Wk1, megaW + 512 * 512,   512, 512, 9, 512 * 512};
    p.w[2]  = {Wv1, megaW + 1024 * 512,  512, 512, 9, 512 * 512};
    p.w[3]  = {Wq2, megaW + 1536 * 512,  256, 256, 9, 256 * 512}; // zero-padded K
    p.w[4]  = {Wo1, o1W,                 512, 512, 9, 512 * 512};
    p.w[5]  = {Wr,  rzW + 0,             256, 512, 9, 256 * 512};
    p.w[6]  = {Wz,  rzW + 256 * 512,     256, 512, 9, 256 * 512};
    p.w[7]  = {Wa,  aW,                  256, 512, 9, 256 * 512};
    p.w[8]  = {Wk2, kvW + 0,             256, 256, 8, 256 * 256};
    p.w[9]  = {Wv2, kvW + 256 * 256,     256, 256, 8, 256 * 256};
    p.w[10] = {Wo2, o2W,                 256, 256, 8, 256 * 256};
    wcast_k<<<dim3(64, 11), blk, 0, stream>>>(p);
  }

  const float sQ1 = 0.18033688011112042f;   // (1/8) * log2(e)
  const float sQ2 = 0.25503490664918414f;   // (1/sqrt(32)) * log2(e)

  // ---- mega QKV1+Q2 projection: fp32 x -> bf16 qkvq[8200][1792] ----
  {
    GemmEpi e;
    e.bias[0] = bq1; e.start[0] = 0;    e.scale[0] = sQ1;
    e.bias[1] = bk1; e.start[1] = 512;  e.scale[1] = 1.f;
    e.bias[2] = bv1; e.start[2] = 1024; e.scale[2] = 1.f;
    e.bias[3] = bq2; e.start[3] = 1536; e.scale[3] = sQ2;
    e.nreg = 4;
    gemm_mfma<1, 1, EP_NONE><<<dim3(14, 65), blk, 0, stream>>>(
        x, 512, megaW, e, qkvq, M1, 1792, 512);
  }

  // ---- attention 1 ----
  attn_mfma<64><<<dim3(17, 64), dim3(128), 0, stream>>>(
      qkvq, qkvq + 512, qkvq + 1024, att1, Tt, Tt,
      Tt * 1792, Tt * 1792, Tt * 512, 1792, 1792, 512);

  // ---- o-proj 1 -> x_self fp32 ----
  {
    GemmEpi e; e.bias[0] = bo1; e.start[0] = 0; e.scale[0] = 1.f; e.nreg = 1;
    gemm_mfma<0, 0, EP_NONE><<<dim3(4, 65), blk, 0, stream>>>(
        att1, 512, o1W, e, x_self, M1, 512, 512);
  }

  // ---- GRU cache update ----
  build_cat<<<(int)((BL2 + 255) / 256), blk, 0, stream>>>(gr_cache, x_self, cat);
  {
    GemmEpi e;
    e.bias[0] = br; e.start[0] = 0;   e.scale[0] = 1.f;
    e.bias[1] = bz; e.start[1] = 256; e.scale[1] = 1.f;
    e.nreg = 2;
    gemm_mfma<0, 0, EP_SIGMOID><<<dim3(4, 16), blk, 0, stream>>>(
        cat, 512, rzW, e, rzg, M2, 512, 512);
  }
  build_cat2<<<(int)((BLA + 255) / 256), blk, 0, stream>>>(gr_cache, rzg, cat);
  {
    GemmEpi e; e.bias[0] = ba; e.start[0] = 0; e.scale[0] = 1.f; e.nreg = 1;
    gemm_mfma<0, 0, EP_GELU><<<dim3(2, 16), blk, 0, stream>>>(
        cat, 512, aW, e, addr_, M2, 256, 512);
  }
  ln_gate<<<M2, blk, 0, stream>>>(addr_, rzg, gr_cache, gamma, beta, gr_new);

  // ---- K2|V2 projection (fused) ----
  {
    GemmEpi e;
    e.bias[0] = bk2; e.start[0] = 0;   e.scale[0] = 1.f;
    e.bias[1] = bv2; e.start[1] = 256; e.scale[1] = 1.f;
    e.nreg = 2;
    gemm_mfma<0, 1, EP_NONE><<<dim3(4, 16), blk, 0, stream>>>(
        gr_new, 256, kvW, e, k2v2, M2, 512, 256);
  }

  // ---- attention 2 (q from qkvq cols 1536.., kv from k2v2) ----
  attn_mfma<32><<<dim3(17, 64), dim3(128), 0, stream>>>(
      qkvq + 1536, k2v2, k2v2 + 256, att2, Tt, Ll,
      Tt * 1792, Ll * 512, Tt * 256, 1792, 512, 256);

  // ---- o-proj 2 -> x_mem fp32 ----
  {
    GemmEpi e; e.bias[0] = bo2; e.start[0] = 0; e.scale[0] = 1.f; e.nreg = 1;
    gemm_mfma<0, 0, EP_NONE><<<dim3(2, 65), blk, 0, stream>>>(
        att2, 256, o2W, e, x_mem, M1, 256, 256);
  }

  // ---- fused conv(pos) + final mix -> d_out ----
  conv_combine<<<dim3(Bc * 32, 2), blk, 0, stream>>>(x, conv_w, conv_b, x_self,
                                                     x_mem, lam, out);
}

// Round 8
// 363.779 us; speedup vs baseline: 4.1074x; 1.0179x over previous
//
#include <hip/hip_runtime.h>
#include <math.h>

typedef unsigned short u16;
typedef unsigned int u32;
typedef __attribute__((ext_vector_type(8))) short short8;
typedef __attribute__((ext_vector_type(4))) short short4v;
typedef __attribute__((ext_vector_type(4))) float f32x4;

// Problem constants
constexpr int Bc = 8;
constexpr int Tt = 1025;
constexpr int Cc = 512;
constexpr int Hn = 8;
constexpr int CA = 256;
constexpr int Ll = 256;

#if __has_builtin(__builtin_amdgcn_exp2f)
#define EXP2F __builtin_amdgcn_exp2f
#else
#define EXP2F exp2f
#endif

__device__ __forceinline__ u16 f2bf(float f) {
  u32 u = __builtin_bit_cast(u32, f);
  u = (u + 0x7FFFu + ((u >> 16) & 1u)) >> 16;
  return (u16)u;
}
// fast pack two fp32 -> bf16x2 (round-half-up): one v_perm
__device__ __forceinline__ u32 pack2f(float lo, float hi) {
  const u32 a = __builtin_bit_cast(u32, hi) + 0x8000u;
  const u32 b = __builtin_bit_cast(u32, lo) + 0x8000u;
  return __builtin_amdgcn_perm(a, b, 0x07060302u);
}

// ---------------------------------------------------------------------------
// Weight cast+transpose into fused layouts: dst[n][k] = k<sK ? W[k][n] : 0
// ---------------------------------------------------------------------------
struct WC { const float* s; u16* d; int sN; int sK; int kshift; int tot; };
struct WCP { WC w[11]; };

__global__ void wcast_k(WCP p) {
  const WC a = p.w[blockIdx.y];
  const int kmask = (1 << a.kshift) - 1;
  for (int idx = blockIdx.x * 256 + threadIdx.x; idx < a.tot; idx += gridDim.x * 256) {
    const int k = idx & kmask;
    const int n = idx >> a.kshift;
    a.d[idx] = (k < a.sK) ? f2bf(a.s[(size_t)k * a.sN + n]) : (u16)0;
  }
}

// ---------------------------------------------------------------------------
// bf16 MFMA GEMM with per-column-region bias/scale map.
// ---------------------------------------------------------------------------
enum { EP_NONE = 0, EP_SIGMOID = 1, EP_GELU = 2 };

struct GemmEpi {
  const float* bias[4];
  int start[4];
  float scale[4];
  int nreg;
};

template <int AF32, int OUTBF, int ACT>
__global__ __launch_bounds__(256) void gemm_mfma(
    const void* __restrict__ Av, int lda,
    const u16* __restrict__ Wt,
    GemmEpi epi,
    void* __restrict__ Cout,
    int M, int N, int K)
{
  __shared__ u16 As[128][32];
  __shared__ u16 Bs[128][32];
  const int tid = threadIdx.x;
  const int m0 = blockIdx.y * 128, n0 = blockIdx.x * 128;
  const int ln = tid & 15, quad = (tid >> 4) & 3, wv = tid >> 6;
  const int wm = (wv & 1) * 64, wn = (wv >> 1) * 64;
  const int sr = tid >> 1;
  const int sk = (tid & 1) * 16;

  f32x4 zf = {0.f, 0.f, 0.f, 0.f};
  f32x4 acc[4][4];
  #pragma unroll
  for (int i = 0; i < 4; i++)
    #pragma unroll
    for (int j = 0; j < 4; j++) acc[i][j] = zf;

  const short8 z8 = {0, 0, 0, 0, 0, 0, 0, 0};

  for (int k0 = 0; k0 < K; k0 += 32) {
    const int gm = m0 + sr;
    short8 a0 = z8, a1 = z8;
    if (gm < M) {
      if (AF32) {
        const float* p = (const float*)Av + (size_t)gm * lda + k0 + sk;
        const float4 f0 = *(const float4*)(p + 0);
        const float4 f1 = *(const float4*)(p + 4);
        const float4 f2 = *(const float4*)(p + 8);
        const float4 f3 = *(const float4*)(p + 12);
        ((u32*)&a0)[0] = pack2f(f0.x, f0.y);
        ((u32*)&a0)[1] = pack2f(f0.z, f0.w);
        ((u32*)&a0)[2] = pack2f(f1.x, f1.y);
        ((u32*)&a0)[3] = pack2f(f1.z, f1.w);
        ((u32*)&a1)[0] = pack2f(f2.x, f2.y);
        ((u32*)&a1)[1] = pack2f(f2.z, f2.w);
        ((u32*)&a1)[2] = pack2f(f3.x, f3.y);
        ((u32*)&a1)[3] = pack2f(f3.z, f3.w);
      } else {
        const u16* p = (const u16*)Av + (size_t)gm * lda + k0 + sk;
        a0 = *(const short8*)p;
        a1 = *(const short8*)(p + 8);
      }
    }
    *(short8*)&As[sr][sk] = a0;
    *(short8*)&As[sr][sk + 8] = a1;
    {
      const u16* q = Wt + (size_t)(n0 + sr) * K + k0 + sk;
      *(short8*)&Bs[sr][sk] = *(const short8*)q;
      *(short8*)&Bs[sr][sk + 8] = *(const short8*)(q + 8);
    }
    __syncthreads();

    short8 af[4], bf[4];
    #pragma unroll
    for (int i = 0; i < 4; i++) af[i] = *(const short8*)&As[wm + i * 16 + ln][quad * 8];
    #pragma unroll
    for (int j = 0; j < 4; j++) bf[j] = *(const short8*)&Bs[wn + j * 16 + ln][quad * 8];
    #pragma unroll
    for (int i = 0; i < 4; i++)
      #pragma unroll
      for (int j = 0; j < 4; j++)
        acc[i][j] = __builtin_amdgcn_mfma_f32_16x16x32_bf16(af[i], bf[j], acc[i][j], 0, 0, 0);
    __syncthreads();
  }

  int ri = 0;
  #pragma unroll
  for (int i = 1; i < 4; i++)
    if (i < epi.nreg && epi.start[i] <= n0) ri = i;
  const float* bp = epi.bias[ri] - epi.start[ri];
  const float sc = epi.scale[ri];

  float bj[4];
  #pragma unroll
  for (int j = 0; j < 4; j++) bj[j] = bp[n0 + wn + j * 16 + ln];

  #pragma unroll
  for (int i = 0; i < 4; i++) {
    #pragma unroll
    for (int r = 0; r < 4; r++) {
      const int gm = m0 + wm + i * 16 + quad * 4 + r;
      if (gm >= M) continue;
      #pragma unroll
      for (int j = 0; j < 4; j++) {
        float v = (acc[i][j][r] + bj[j]) * sc;
        if (ACT == EP_SIGMOID)   v = 1.f / (1.f + __expf(-v));
        else if (ACT == EP_GELU) v = 0.5f * v * (1.f + erff(v * 0.70710678118654752f));
        const size_t off = (size_t)gm * N + n0 + wn + j * 16 + ln;
        if (OUTBF) ((u16*)Cout)[off] = f2bf(v);
        else       ((float*)Cout)[off] = v;
      }
    }
  }
}

// ---------------------------------------------------------------------------
// MFMA flash attention v6.  Block = 128 thr = 2 waves, each wave 32 q rows.
// S^T = K.Q^T; no-max softmax p = exp2(s), scale*log2e folded into Q proj.
// K fragments from global; V staged to LDS (dbuf, 1 barrier/iter).
// SOFTWARE PIPELINE: K-frags + V-rows for iteration it+1 are loaded
// (global->reg) before the barrier of iteration it, hiding global latency
// under softmax+PV compute.  Loads are branch-free: key row clamped to Tk-1
// (garbage keys get p=0 in softmax, 0*V=0 in PV).
// ---------------------------------------------------------------------------
template <int DH>
__global__ __launch_bounds__(128) void attn_mfma(
    const u16* __restrict__ Qp, const u16* __restrict__ Kp,
    const u16* __restrict__ Vp, u16* __restrict__ Op,
    int Tq, int Tk, int qbs, int kbs, int obs, int qrs, int krs, int ors)
{
  constexpr int NC = DH / 32;      // score k-chunks
  constexpr int NM = DH / 16;      // output d-tiles

  __shared__ u16 Vt[2][DH * 32];
  __shared__ u16 Pb[2 * 32 * 32];

  const int b = blockIdx.y >> 3, h = blockIdx.y & 7;
  const int q0 = blockIdx.x * 64;
  const int tid = threadIdx.x;
  const int wv = tid >> 6;
  const int lane = tid & 63;
  const int ln = lane & 15, quad = lane >> 4;

  const u16* Qb = Qp + (size_t)b * qbs + h * DH;
  const u16* Kb = Kp + (size_t)b * kbs + h * DH;
  const u16* Vb = Vp + (size_t)b * kbs + h * DH;
  u16* Ob = Op + (size_t)b * obs + h * DH;

  const short8 z8 = {0, 0, 0, 0, 0, 0, 0, 0};
  const f32x4 zf = {0.f, 0.f, 0.f, 0.f};

  // Q fragments (B-operand = Q^T), resident across K loop
  short8 qf[2][NC];
  #pragma unroll
  for (int qs = 0; qs < 2; qs++) {
    const int gq = q0 + wv * 32 + qs * 16 + ln;
    #pragma unroll
    for (int c = 0; c < NC; c++) {
      if (gq < Tq) qf[qs][c] = *(const short8*)(Qb + (size_t)gq * qrs + c * 32 + quad * 8);
      else         qf[qs][c] = z8;
    }
  }

  f32x4 oacc[2][NM];
  float lsum[2] = {0.f, 0.f};
  #pragma unroll
  for (int qs = 0; qs < 2; qs++)
    #pragma unroll
    for (int c = 0; c < NM; c++) oacc[qs][c] = zf;

  // V staging maps
  const int vd0 = (tid & 15) * (DH / 16);
  const int vk = (tid >> 4) * 4;
  const int gb = vk >> 3, off = vk & 7;

  const int nfull = Tk >> 5;
  const int nit = (Tk + 31) >> 5;
  const int tkm1 = Tk - 1;

  // branch-free prefetchers (row clamped to Tk-1)
  auto loadK = [&](int it, short8 (&kf)[2][NC]) {
    #pragma unroll
    for (int kc = 0; kc < 2; kc++)
      #pragma unroll
      for (int c = 0; c < NC; c++) {
        int row = (it << 5) + kc * 16 + ln;
        row = row < tkm1 ? row : tkm1;
        kf[kc][c] = *(const short8*)(Kb + (size_t)row * krs + c * 32 + quad * 8);
      }
  };
  auto loadV = [&](int it, short4v (&vr)[4]) {
    #pragma unroll
    for (int i2 = 0; i2 < 4; i2++) {
      int gk = (it << 5) + vk + i2;
      gk = gk < tkm1 ? gk : tkm1;
      short4v t = {0, 0, 0, 0};
      if (DH == 64) {
        t = *(const short4v*)(Vb + (size_t)gk * krs + vd0);
      } else {
        ushort2 u = *(const ushort2*)(Vb + (size_t)gk * krs + vd0);
        t[0] = (short)u.x; t[1] = (short)u.y;
      }
      vr[i2] = t;
    }
  };

  auto body = [&](int it, short8 (&kfC)[2][NC], short4v (&vrC)[4],
                  short8 (&kfN)[2][NC], short4v (&vrN)[4]) {
    const bool full = (it < nfull);
    u16* vt = &Vt[it & 1][0];
    const int k0 = it << 5;

    // ---- stage V (from prefetched regs) into Vt[it&1], swizzled b64 ----
    #pragma unroll
    for (int i = 0; i < DH / 16; i++) {
      const int d = vd0 + i;
      const int h2 = (d ^ (d >> 3)) & 3;
      short4v w = {vrC[0][i], vrC[1][i], vrC[2][i], vrC[3][i]};
      *(short4v*)&vt[d * 32 + ((gb ^ h2) << 3) + off] = w;
    }
    // ---- prefetch next iteration (overlaps with compute below) ----
    if (it + 1 < nit) { loadK(it + 1, kfN); loadV(it + 1, vrN); }
    __syncthreads();

    // ---- scores S^T, exp2, pack P (swizzled b64 writes) ----
    #pragma unroll
    for (int qs = 0; qs < 2; qs++) {
      #pragma unroll
      for (int kc = 0; kc < 2; kc++) {
        f32x4 s = zf;
        #pragma unroll
        for (int c = 0; c < NC; c++)
          s = __builtin_amdgcn_mfma_f32_16x16x32_bf16(kfC[kc][c], qf[qs][c], s, 0, 0, 0);
        float p0, p1, p2, p3;
        if (full) {
          p0 = EXP2F(s[0]); p1 = EXP2F(s[1]); p2 = EXP2F(s[2]); p3 = EXP2F(s[3]);
        } else {
          const int kb = k0 + kc * 16 + quad * 4;
          p0 = (kb + 0 < Tk) ? EXP2F(s[0]) : 0.f;
          p1 = (kb + 1 < Tk) ? EXP2F(s[1]) : 0.f;
          p2 = (kb + 2 < Tk) ? EXP2F(s[2]) : 0.f;
          p3 = (kb + 3 < Tk) ? EXP2F(s[3]) : 0.f;
        }
        lsum[qs] += (p0 + p1) + (p2 + p3);
        short4v pw;
        ((u32*)&pw)[0] = pack2f(p0, p1);
        ((u32*)&pw)[1] = pack2f(p2, p3);
        const int q = qs * 16 + ln;
        const int g = ((kc * 2 + (quad >> 1)) ^ (ln & 3)) & 3;
        *(short4v*)&Pb[wv * 1024 + q * 32 + (g << 3) + (quad & 1) * 4] = pw;
      }
    }

    // ---- PV: O += P.V (per-wave Pb, no barrier) ----
    short8 pf2[2];
    #pragma unroll
    for (int qs = 0; qs < 2; qs++) {
      const int q = qs * 16 + ln;
      const int g = quad ^ (ln & 3);
      pf2[qs] = *(const short8*)&Pb[wv * 1024 + q * 32 + g * 8];
    }
    #pragma unroll
    for (int c = 0; c < NM; c++) {
      const int d = c * 16 + ln;
      const int g = quad ^ ((d ^ (d >> 3)) & 3);
      const short8 vf = *(const short8*)&vt[d * 32 + g * 8];
      #pragma unroll
      for (int qs = 0; qs < 2; qs++)
        oacc[qs][c] = __builtin_amdgcn_mfma_f32_16x16x32_bf16(pf2[qs], vf, oacc[qs][c], 0, 0, 0);
    }
  };

  short8 kfA[2][NC], kfB[2][NC];
  short4v vrA[4], vrB[4];
  loadK(0, kfA);
  loadV(0, vrA);

  int it = 0;
  for (; it + 1 < nit; it += 2) {
    body(it, kfA, vrA, kfB, vrB);
    body(it + 1, kfB, vrB, kfA, vrA);
  }
  if (it < nit) body(it, kfA, vrA, kfB, vrB);

  // ---- epilogue: reduce l across quads, divide, store ----
  float lq[2];
  #pragma unroll
  for (int qs = 0; qs < 2; qs++) {
    float t = lsum[qs];
    t += __shfl_xor(t, 16);
    t += __shfl_xor(t, 32);
    lq[qs] = t;
  }
  #pragma unroll
  for (int qs = 0; qs < 2; qs++) {
    #pragma unroll
    for (int r = 0; r < 4; r++) {
      const float linv = 1.f / __shfl(lq[qs], quad * 4 + r);
      const int gq = q0 + wv * 32 + qs * 16 + quad * 4 + r;
      if (gq >= Tq) continue;
      #pragma unroll
      for (int c = 0; c < NM; c++)
        Ob[(size_t)gq * ors + c * 16 + ln] = f2bf(oacc[qs][c][r] * linv);
    }
  }
}

// ---------------------------------------------------------------------------
// FUSED grouped-conv (pos) + final combine (register-window sliding conv).
// ---------------------------------------------------------------------------
__global__ __launch_bounds__(256) void conv_combine(
    const float* __restrict__ x, const float* __restrict__ cw,
    const float* __restrict__ cb, const float* __restrict__ x_self,
    const float* __restrict__ x_mem, const float* __restrict__ lam,
    float* __restrict__ out)
{
  const int bh = blockIdx.x;               // b*32 + h
  const int b = bh >> 5, hh = bh & 31;
  const int c = (blockIdx.y << 8) + threadIdx.x;   // 0..511
  const int ci = c & ~1;
  const int dd = c & 63;
  const int h8 = c >> 6;
  const float alpha = 1.f / (1.f + __expf(-lam[h8]));
  const float bias = cb[c];

  float wgt[2][9];
  #pragma unroll
  for (int ch = 0; ch < 2; ch++)
    #pragma unroll
    for (int k = 0; k < 9; k++) wgt[ch][k] = cw[c * 18 + ch * 9 + k];

  const float* xrow[3];
  bool rv[3];
  #pragma unroll
  for (int r = 0; r < 3; r++) {
    const int h2 = hh + r - 1;
    rv[r] = (unsigned)h2 < 32u;
    xrow[r] = x + ((size_t)(b * Tt) + 1 + h2 * 32) * Cc + ci;
  }

  float2 win[3][3];
  #pragma unroll
  for (int r = 0; r < 3; r++) {
    win[r][0] = make_float2(0.f, 0.f);
    win[r][1] = rv[r] ? *(const float2*)(xrow[r]) : make_float2(0.f, 0.f);
  }

  const size_t bT = (size_t)b * Tt;
  for (int w = 0; w < 32; w++) {
    #pragma unroll
    for (int r = 0; r < 3; r++)
      win[r][2] = (rv[r] && w + 1 < 32) ? *(const float2*)(xrow[r] + (w + 1) * Cc)
                                        : make_float2(0.f, 0.f);
    float pos = bias;
    #pragma unroll
    for (int r = 0; r < 3; r++)
      #pragma unroll
      for (int col = 0; col < 3; col++) {
        pos += win[r][col].x * wgt[0][r * 3 + col];
        pos += win[r][col].y * wgt[1][r * 3 + col];
      }
    const size_t bt = bT + 1 + hh * 32 + w;
    const float mem = (dd < 32) ? x_mem[bt * 256 + h8 * 32 + dd] : 0.f;
    out[bt * 512 + c] = pos + alpha * mem + (1.f - alpha) * x_self[bt * 512 + c];
    #pragma unroll
    for (int r = 0; r < 3; r++) { win[r][0] = win[r][1]; win[r][1] = win[r][2]; }
  }

  if (hh == 0) {
    const float mem = (dd < 32) ? x_mem[bT * 256 + h8 * 32 + dd] : 0.f;
    out[bT * 512 + c] = alpha * mem + (1.f - alpha) * x_self[bT * 512 + c];
  }
}

// cat = [gr (bcast) | x_summary] bf16
__global__ void build_cat(const float* __restrict__ gr_cache,
                          const float* __restrict__ x_self,
                          u16* __restrict__ cat)
{
  const int idx = blockIdx.x * 256 + threadIdx.x;
  if (idx >= Bc * Ll * 512) return;
  const int k = idx & 511;
  const int bi = idx >> 9;
  const int i = bi & 255;
  const int b = bi >> 8;
  float v;
  if (k < 256) v = gr_cache[i * 256 + k];
  else         v = x_self[((size_t)(b * Tt + 4 * i)) * Cc + (k - 256)];
  cat[idx] = f2bf(v);
}

// cat[:, :256] = bf16(reset * gr); reset = rzg cols 0..255
__global__ void build_cat2(const float* __restrict__ gr_cache,
                           const float* __restrict__ rzg,
                           u16* __restrict__ cat)
{
  const int idx = blockIdx.x * 256 + threadIdx.x;
  if (idx >= Bc * Ll * 256) return;
  const int k = idx & 255;
  const int bi = idx >> 8;
  const int i = bi & 255;
  cat[(size_t)bi * 512 + k] = f2bf(gr_cache[i * 256 + k] * rzg[(size_t)bi * 512 + k]);
}

// LayerNorm + gate -> gr_new bf16 ; z = rzg cols 256..511
__device__ inline float block_sum256(float v, float* red)
{
  #pragma unroll
  for (int o = 32; o >= 1; o >>= 1) v += __shfl_down(v, o);
  const int wid = threadIdx.x >> 6;
  if ((threadIdx.x & 63) == 0) red[wid] = v;
  __syncthreads();
  const float t = red[0] + red[1] + red[2] + red[3];
  __syncthreads();
  return t;
}

__global__ __launch_bounds__(256) void ln_gate(
    const float* __restrict__ add_raw, const float* __restrict__ rzg,
    const float* __restrict__ gr_cache, const float* __restrict__ gamma,
    const float* __restrict__ beta, u16* __restrict__ gr_new)
{
  __shared__ float red[4];
  const int bi = blockIdx.x;
  const int i = bi & 255;
  const int c = threadIdx.x;
  const float v = add_raw[(size_t)bi * 256 + c];
  const float mu = block_sum256(v, red) * (1.f / 256.f);
  const float dv = v - mu;
  const float var = block_sum256(dv * dv, red) * (1.f / 256.f);
  const float nrm = dv * rsqrtf(var + 1e-5f) * gamma[c] + beta[c];
  const float zz = rzg[(size_t)bi * 512 + 256 + c];
  gr_new[(size_t)bi * 256 + c] = f2bf(zz * nrm + (1.f - zz) * gr_cache[i * 256 + c]);
}

// ---------------------------------------------------------------------------
extern "C" void kernel_launch(void* const* d_in, const int* in_sizes, int n_in,
                              void* d_out, int out_size, void* d_ws, size_t ws_size,
                              hipStream_t stream)
{
  const float* x        = (const float*)d_in[0];
  const float* gr_cache = (const float*)d_in[1];
  const float* Wq1 = (const float*)d_in[2];  const float* bq1 = (const float*)d_in[3];
  const float* Wk1 = (const float*)d_in[4];  const float* bk1 = (const float*)d_in[5];
  const float* Wv1 = (const float*)d_in[6];  const float* bv1 = (const float*)d_in[7];
  const float* Wo1 = (const float*)d_in[8];  const float* bo1 = (const float*)d_in[9];
  const float* Wq2 = (const float*)d_in[10]; const float* bq2 = (const float*)d_in[11];
  const float* Wk2 = (const float*)d_in[12]; const float* bk2 = (const float*)d_in[13];
  const float* Wv2 = (const float*)d_in[14]; const float* bv2 = (const float*)d_in[15];
  const float* Wo2 = (const float*)d_in[16]; const float* bo2 = (const float*)d_in[17];
  const float* Wr  = (const float*)d_in[18]; const float* br  = (const float*)d_in[19];
  const float* Wz  = (const float*)d_in[20]; const float* bz  = (const float*)d_in[21];
  const float* Wa  = (const float*)d_in[22]; const float* ba  = (const float*)d_in[23];
  const float* gamma = (const float*)d_in[24];
  const float* beta  = (const float*)d_in[25];
  const float* lam   = (const float*)d_in[26];
  const float* conv_w = (const float*)d_in[27];
  const float* conv_b = (const float*)d_in[28];
  float* out = (float*)d_out;

  const int M1 = Bc * Tt;       // 8200
  const int M2 = Bc * Ll;       // 2048
  const size_t BLA = (size_t)Bc * Ll * CA;
  const size_t BL2 = (size_t)Bc * Ll * 512;

  char* W = (char*)d_ws;
  u16*   qkvq  = (u16*)(W + 0);           // [8200][1792] = 29,388,800 B
  u16*   att1  = (u16*)(W + 29388800);    // [8200][512]  =  8,396,800 B
  u16*   att2  = (u16*)(W + 29388800);    // reuse (att1 dead after o1)
  float* x_self= (float*)(W + 37785600);  // [8200][512] f32 = 16,793,600
  u16*   cat   = (u16*)(W + 54579200);    // [2048][512] = 2,097,152
  float* rzg   = (float*)(W + 56676352);  // [2048][512] f32 = 4,194,304
  float* addr_ = (float*)(W + 60870656);  // [2048][256] f32 = 2,097,152
  float* x_mem = (float*)(W + 54579200);  // reuse cat/rzg/addr after ln_gate
  u16*   gr_new= (u16*)(W + 62976000);    // [2048][256] = 1,048,576
  u16*   k2v2  = (u16*)(W + 64024576);    // [2048][512] = 2,097,152
  u16*   wtb   = (u16*)(W + 66121728);    // 3,538,944 B -> end 69,660,672

  u16* megaW = wtb;                 // [1792][512]
  u16* o1W   = wtb + 917504;        // [512][512]
  u16* rzW   = wtb + 1179648;       // [512][512]
  u16* aW    = wtb + 1441792;       // [256][512]
  u16* kvW   = wtb + 1572864;       // [512][256]
  u16* o2W   = wtb + 1703936;       // [256][256]

  const dim3 blk(256);

  // ---- weight casts into fused layouts ----
  {
    WCP p;
    p.w[0]  = {Wq1, megaW + 0,           512, 512, 9, 512 * 512};
    p.w[1]  = {Wk1, megaW + 512 * 512,   512, 512, 9, 512 * 512};
    p.w[2]  = {Wv1, megaW + 1024 * 512,  512, 512, 9, 512 * 512};
    p.w[3]  = {Wq2, megaW + 1536 * 512,  256, 256, 9, 256 * 512}; // zero-padded K
    p.w[4]  = {Wo1, o1W,                 512, 512, 9, 512 * 512};
    p.w[5]  = {Wr,  rzW + 0,             256, 512, 9, 256 * 512};
    p.w[6]  = {Wz,  rzW + 256 * 512,     256, 512, 9, 256 * 512};
    p.w[7]  = {Wa,  aW,                  256, 512, 9, 256 * 512};
    p.w[8]  = {Wk2, kvW + 0,             256, 256, 8, 256 * 256};
    p.w[9]  = {Wv2, kvW + 256 * 256,     256, 256, 8, 256 * 256};
    p.w[10] = {Wo2, o2W,                 256, 256, 8, 256 * 256};
    wcast_k<<<dim3(64, 11), blk, 0, stream>>>(p);
  }

  const float sQ1 = 0.18033688011112042f;   // (1/8) * log2(e)
  const float sQ2 = 0.25503490664918414f;   // (1/sqrt(32)) * log2(e)

  // ---- mega QKV1+Q2 projection: fp32 x -> bf16 qkvq[8200][1792] ----
  {
    GemmEpi e;
    e.bias[0] = bq1; e.start[0] = 0;    e.scale[0] = sQ1;
    e.bias[1] = bk1; e.start[1] = 512;  e.scale[1] = 1.f;
    e.bias[2] = bv1; e.start[2] = 1024; e.scale[2] = 1.f;
    e.bias[3] = bq2; e.start[3] = 1536; e.scale[3] = sQ2;
    e.nreg = 4;
    gemm_mfma<1, 1, EP_NONE><<<dim3(14, 65), blk, 0, stream>>>(
        x, 512, megaW, e, qkvq, M1, 1792, 512);
  }

  // ---- attention 1 ----
  attn_mfma<64><<<dim3(17, 64), dim3(128), 0, stream>>>(
      qkvq, qkvq + 512, qkvq + 1024, att1, Tt, Tt,
      Tt * 1792, Tt * 1792, Tt * 512, 1792, 1792, 512);

  // ---- o-proj 1 -> x_self fp32 ----
  {
    GemmEpi e; e.bias[0] = bo1; e.start[0] = 0; e.scale[0] = 1.f; e.nreg = 1;
    gemm_mfma<0, 0, EP_NONE><<<dim3(4, 65), blk, 0, stream>>>(
        att1, 512, o1W, e, x_self, M1, 512, 512);
  }

  // ---- GRU cache update ----
  build_cat<<<(int)((BL2 + 255) / 256), blk, 0, stream>>>(gr_cache, x_self, cat);
  {
    GemmEpi e;
    e.bias[0] = br; e.start[0] = 0;   e.scale[0] = 1.f;
    e.bias[1] = bz; e.start[1] = 256; e.scale[1] = 1.f;
    e.nreg = 2;
    gemm_mfma<0, 0, EP_SIGMOID><<<dim3(4, 16), blk, 0, stream>>>(
        cat, 512, rzW, e, rzg, M2, 512, 512);
  }
  build_cat2<<<(int)((BLA + 255) / 256), blk, 0, stream>>>(gr_cache, rzg, cat);
  {
    GemmEpi e; e.bias[0] = ba; e.start[0] = 0; e.scale[0] = 1.f; e.nreg = 1;
    gemm_mfma<0, 0, EP_GELU><<<dim3(2, 16), blk, 0, stream>>>(
        cat, 512, aW, e, addr_, M2, 256, 512);
  }
  ln_gate<<<M2, blk, 0, stream>>>(addr_, rzg, gr_cache, gamma, beta, gr_new);

  // ---- K2|V2 projection (fused) ----
  {
    GemmEpi e;
    e.bias[0] = bk2; e.start[0] = 0;   e.scale[0] = 1.f;
    e.bias[1] = bv2; e.start[1] = 256; e.scale[1] = 1.f;
    e.nreg = 2;
    gemm_mfma<0, 1, EP_NONE><<<dim3(4, 16), blk, 0, stream>>>(
        gr_new, 256, kvW, e, k2v2, M2, 512, 256);
  }

  // ---- attention 2 (q from qkvq cols 1536.., kv from k2v2) ----
  attn_mfma<32><<<dim3(17, 64), dim3(128), 0, stream>>>(
      qkvq + 1536, k2v2, k2v2 + 256, att2, Tt, Ll,
      Tt * 1792, Ll * 512, Tt * 256, 1792, 512, 256);

  // ---- o-proj 2 -> x_mem fp32 ----
  {
    GemmEpi e; e.bias[0] = bo2; e.start[0] = 0; e.scale[0] = 1.f; e.nreg = 1;
    gemm_mfma<0, 0, EP_NONE><<<dim3(2, 65), blk, 0, stream>>>(
        att2, 256, o2W, e, x_mem, M1, 256, 256);
  }

  // ---- fused conv(pos) + final mix -> d_out ----
  conv_combine<<<dim3(Bc * 32, 2), blk, 0, stream>>>(x, conv_w, conv_b, x_self,
                                                     x_mem, lam, out);
}